// Round 13
// baseline (719.815 us; speedup 1.0000x reference)
//
#include <hip/hip_runtime.h>
#include <cmath>

namespace {
constexpr int Bn = 128, Tn = 128, BTn = Bn * Tn;
constexpr int CONTn = 16, HIDn = 128, EMBn = 64;
constexpr int Kn = 8192, CEn = 6, VSPn = 2000, VLCn = 32, FINn = 3 * HIDn;
constexpr int VSP_PAD = 2048;             // padded vocab for MFMA tiles
constexpr int CAP = 128;                  // max stored VQ candidates per token
constexpr float EPSC = 0.02f;             // rigorous bf16 interval coeff (2^-6 * 1.28)
constexpr int TOKB = 32;                  // tokens per sweep block
constexpr int KCW = 64;                   // codes per wave-chunk
constexpr int NIT = Kn / (KCW * 8);       // 16 chunk-iterations per wave (8 waves)

// ---- workspace layout (float units) ----
constexpr size_t WS_NAIP2 = 0;                               // B*HID
constexpr size_t WS_ZE    = WS_NAIP2 + (size_t)Bn * HIDn;    // BT*EMB
constexpr size_t WS_ZQ    = WS_ZE + (size_t)BTn * EMBn;      // BT*EMB
constexpr size_t WS_H     = WS_ZQ + (size_t)BTn * EMBn;      // BT*HID
constexpr size_t WS_ESQ   = WS_H + (size_t)BTn * HIDn;       // K
constexpr size_t WS_PART  = WS_ESQ + Kn;                     // BT/4 partial loss sums
constexpr size_t WS_CNTK  = WS_PART + BTn / 4;               // K ints (code counts)
constexpr size_t WS_CNTT  = WS_CNTK + Kn;                    // BT ints (candidate counts)
constexpr size_t WS_Q     = WS_CNTT + BTn;                   // BT floats (eps per token)
constexpr size_t WS_CAND  = WS_Q + BTn;                      // BT*CAP ints
constexpr size_t WS_ZBF   = WS_CAND + (size_t)BTn * CAP;     // BT*EMB ushort
constexpr size_t WS_CBBF  = WS_ZBF + (size_t)BTn * EMBn / 2; // K*EMB ushort
constexpr size_t WS_HBF   = WS_CBBF + (size_t)Kn * EMBn / 2; // BT*HID ushort
constexpr size_t WS_WBF   = WS_HBF + (size_t)BTn * HIDn / 2; // VSP_PAD*HID ushort
constexpr size_t WS_RCG   = WS_WBF + (size_t)VSP_PAD * HIDn / 2; // 1 float (global rcmax)
constexpr size_t WS_FUSED = WS_RCG + 1;                      // BT*FIN floats
constexpr size_t WS_H1    = WS_FUSED + (size_t)BTn * FINn;   // BT*HID floats

// ---- output layout (float units) ----
constexpr size_t O_CONT = 0;
constexpr size_t O_SP   = O_CONT + (size_t)BTn * CONTn;
constexpr size_t O_LC   = O_SP + (size_t)BTn * VSPn;
constexpr size_t O_CAN  = O_LC + (size_t)BTn * VLCn;
constexpr size_t O_IDX  = O_CAN + Bn;
constexpr size_t O_LOSS = O_IDX + BTn;
constexpr size_t O_PPL  = O_LOSS + 1;
} // namespace

typedef __attribute__((ext_vector_type(8))) short short8v;  // 8 bf16 = 4 VGPR
typedef __attribute__((ext_vector_type(4))) float f32x4;

__device__ __forceinline__ float nan0(float v) {
    return __builtin_isfinite(v) ? v : 0.0f;
}
__device__ __forceinline__ float dot4(float4 a, float4 b) {
    return a.x * b.x + a.y * b.y + a.z * b.z + a.w * b.w;
}
__device__ __forceinline__ unsigned short f2bf(float f) { // RNE, finite-only
    union { float f; unsigned u; } v{f};
    unsigned r = v.u + 0x7FFFu + ((v.u >> 16) & 1u);
    return (unsigned short)(r >> 16);
}
// monotone float<->uint encoding (for atomicMax on floats of any sign)
__device__ __forceinline__ unsigned fenc(float f) {
    unsigned b = __float_as_uint(f);
    return (b & 0x80000000u) ? ~b : (b | 0x80000000u);
}
__device__ __forceinline__ float fdec(unsigned k) {
    unsigned b = (k >> 31) ? (k & 0x7fffffffu) : ~k;
    return __uint_as_float(b);
}

// ---------------------------------------------------------------- K0: zero code counts + e_sq + bf16 codebook
__global__ __launch_bounds__(256) void k_esq_zero(const float* __restrict__ cb,
                                                  float* __restrict__ e_sq,
                                                  int* __restrict__ counts,
                                                  unsigned short* __restrict__ cbbf) {
    int i = blockIdx.x * 256 + threadIdx.x;
    if (i < Kn) {
        counts[i] = 0;
        const float4* r = (const float4*)(cb + (size_t)i * EMBn);
        float s = 0.f;
#pragma unroll
        for (int j = 0; j < 16; ++j) {
            float4 v = r[j];
            s += dot4(v, v);
            unsigned short u[4] = {f2bf(v.x), f2bf(v.y), f2bf(v.z), f2bf(v.w)};
            *(uint2*)(cbbf + (size_t)i * EMBn + j * 4) = *(const uint2*)u;
        }
        e_sq[i] = s;
    }
}

// ---------------------------------------------------------------- K0c: global max codebook norm
__global__ __launch_bounds__(256) void k_rcmax(const float* __restrict__ e_sq,
                                               float* __restrict__ rcg) {
    const int tid = threadIdx.x;
    float m = 0.f;
#pragma unroll
    for (int j = 0; j < Kn / 256; ++j) m = fmaxf(m, e_sq[j * 256 + tid]);
#pragma unroll
    for (int off = 32; off > 0; off >>= 1) m = fmaxf(m, __shfl_xor(m, off));
    __shared__ float wm[4];
    if ((tid & 63) == 0) wm[tid >> 6] = m;
    __syncthreads();
    if (tid == 0)
        rcg[0] = sqrtf(fmaxf(fmaxf(wm[0], wm[1]), fmaxf(wm[2], wm[3]))) * 1.000001f;
}

// ---------------------------------------------------------------- K0b: sp_head_w -> bf16, padded to 2048 rows
__global__ __launch_bounds__(256) void k_wcast(const float* __restrict__ w,
                                               unsigned short* __restrict__ wbf) {
    int i = blockIdx.x * 256 + threadIdx.x;      // float4 index; 32 per row
    int v = i >> 5;
    unsigned short u[4] = {0, 0, 0, 0};
    if (v < VSPn) {
        float4 x = ((const float4*)w)[i];
        u[0] = f2bf(x.x); u[1] = f2bf(x.y); u[2] = f2bf(x.z); u[3] = f2bf(x.w);
    }
    *(uint2*)(wbf + (size_t)i * 4) = *(const uint2*)u;
}

// ---------------------------------------------------------------- K1: naip conv + proj -> naip2 (B x HID)
__global__ __launch_bounds__(128) void k_naip(const float* __restrict__ naip,
                                              const float* __restrict__ conv_w,
                                              const float* __restrict__ conv_b,
                                              const float* __restrict__ pw,
                                              const float* __restrict__ pb,
                                              float* __restrict__ naip2) {
    int b = blockIdx.x, o = threadIdx.x;
    __shared__ float feat[HIDn];
    float acc = conv_b[o];
#pragma unroll
    for (int i = 0; i < 9; ++i) acc += nan0(naip[b * 9 + i]) * conv_w[o * 9 + i];
    feat[o] = fmaxf(acc, 0.f);
    __syncthreads();
    float a2 = pb[o];
    const float4* wr = (const float4*)(pw + (size_t)o * HIDn);
    const float4* fr = (const float4*)feat;
#pragma unroll
    for (int j = 0; j < 32; ++j) a2 += dot4(fr[j], wr[j]);
    naip2[(size_t)b * HIDn + o] = a2;
}

// ---------------------------------------------------------------- K2a: build fused[BT][384] (bit-identical formulas)
__global__ __launch_bounds__(256) void k_fused(
    const float* __restrict__ cont, const int* __restrict__ cat,
    const float* __restrict__ emb_sp, const float* __restrict__ emb_lc,
    const float* __restrict__ cpw, const float* __restrict__ cpb,
    const float* __restrict__ caw, const float* __restrict__ cab,
    const float* __restrict__ naip2, float* __restrict__ fused_g) {
    const int tok0 = blockIdx.x * 64;
    const int tid = threadIdx.x;
    // sec0: naip broadcast
    for (int idx = tid; idx < 64 * HIDn; idx += 256) {
        int t = idx >> 7, j = idx & 127;
        int tok = tok0 + t;
        fused_g[(size_t)tok * FINn + j] = naip2[(size_t)(tok >> 7) * HIDn + j];
    }
    // sec1: cont projection
    for (int idx = tid; idx < 64 * HIDn; idx += 256) {
        int t = idx >> 7, o = idx & 127;
        int tok = tok0 + t;
        const float4* cp = (const float4*)(cont + (size_t)tok * CONTn);
        const float4* wr = (const float4*)(cpw + (size_t)o * CONTn);
        float a = cpb[o];
#pragma unroll
        for (int q = 0; q < 4; ++q) {
            float4 c4 = cp[q], w4 = wr[q];
            a += nan0(c4.x) * w4.x + nan0(c4.y) * w4.y + nan0(c4.z) * w4.z + nan0(c4.w) * w4.w;
        }
        fused_g[(size_t)tok * FINn + HIDn + o] = a;
    }
    // sec2: cat embedding projection
    for (int idx = tid; idx < 64 * HIDn; idx += 256) {
        int t = idx >> 7, o = idx & 127;
        int tok = tok0 + t;
        int c0 = cat[tok * 2], c1 = cat[tok * 2 + 1];
        const float* e0 = emb_sp + (size_t)c0 * CEn;
        const float* e1 = emb_lc + (size_t)c1 * CEn;
        const float* wr = caw + (size_t)o * (2 * CEn);
        float a = cab[o];
#pragma unroll
        for (int i = 0; i < CEn; ++i) a += e0[i] * wr[i];
#pragma unroll
        for (int i = 0; i < CEn; ++i) a += e1[i] * wr[CEn + i];
        fused_g[(size_t)tok * FINn + 2 * HIDn + o] = a;
    }
}

// ---------------------------------------------------------------- K2b: fuse1 GEMM (64-tok x 128-out tile, f32, swizzled LDS)
// grid BTn/64; 256 threads; per-thread 4 toks x 8 outs; K=384 in 12 slices of 32.
// acc init = f1b (same chain start as original); kk ascending => h1 bit-identical.
// LDS swizzle: ht p = row*8 + (c4 ^ ((row>>2)&3)); wt p = row*8 + (c4 ^ (row&7)).
__global__ __launch_bounds__(256, 4) void k_f1(const float* __restrict__ fused_g,
                                               const float* __restrict__ f1w,
                                               const float* __restrict__ f1b,
                                               float* __restrict__ h1g) {
    const int tid = threadIdx.x;
    const int x = tid & 15, y = tid >> 4;
    const int tok0 = blockIdx.x * 64;
    __shared__ __align__(16) float ht[64 * 32];
    __shared__ __align__(16) float wt[128 * 32];

    float acc[4][8];
#pragma unroll
    for (int j = 0; j < 8; ++j) {
        float bv = f1b[x + 16 * j];
#pragma unroll
        for (int t = 0; t < 4; ++t) acc[t][j] = bv;
    }

    for (int s = 0; s < 12; ++s) {
        __syncthreads();
#pragma unroll
        for (int w = 0; w < 2; ++w) {
            int idx = tid + w * 256;
            int row = idx >> 3, c4 = idx & 7;
            float4 v = *(const float4*)(fused_g + (size_t)(tok0 + row) * FINn + s * 32 + c4 * 4);
            ((float4*)ht)[row * 8 + (c4 ^ ((row >> 2) & 3))] = v;
        }
#pragma unroll
        for (int w = 0; w < 4; ++w) {
            int idx = tid + w * 256;
            int row = idx >> 3, c4 = idx & 7;
            float4 v = *(const float4*)(f1w + (size_t)row * FINn + s * 32 + c4 * 4);
            ((float4*)wt)[row * 8 + (c4 ^ (row & 7))] = v;
        }
        __syncthreads();
#pragma unroll
        for (int kk = 0; kk < 8; ++kk) {
            float4 hh[4], ww[8];
#pragma unroll
            for (int t = 0; t < 4; ++t) {
                int row = y * 4 + t;
                hh[t] = ((const float4*)ht)[row * 8 + (kk ^ ((row >> 2) & 3))];
            }
#pragma unroll
            for (int j = 0; j < 8; ++j) {
                int row = x + 16 * j;
                ww[j] = ((const float4*)wt)[row * 8 + (kk ^ (row & 7))];
            }
#pragma unroll
            for (int t = 0; t < 4; ++t)
#pragma unroll
                for (int j = 0; j < 8; ++j) acc[t][j] += dot4(hh[t], ww[j]);
        }
    }
#pragma unroll
    for (int t = 0; t < 4; ++t)
#pragma unroll
        for (int j = 0; j < 8; ++j)
            h1g[(size_t)(tok0 + y * 4 + t) * HIDn + x + 16 * j] = fmaxf(acc[t][j], 0.f);
}

// ---------------------------------------------------------------- K2c: z_e = h1 @ f2w^T + b (verbatim original C-phase)
__global__ __launch_bounds__(256) void k_f2(const float* __restrict__ h1g,
                                            const float* __restrict__ f2w,
                                            const float* __restrict__ f2b,
                                            float* __restrict__ z_e) {
    const int tok0 = blockIdx.x * 16;
    const int tid = threadIdx.x;
    __shared__ float h1[16][HIDn + 4];
    for (int idx = tid; idx < 16 * 32; idx += 256) {
        int t = idx >> 5, q = idx & 31;
        ((float4*)&h1[t][0])[q] = ((const float4*)(h1g + (size_t)(tok0 + t) * HIDn))[q];
    }
    __syncthreads();
    int o = tid & 63, tg = tid >> 6;
    float acc[4];
    float bv = f2b[o];
#pragma unroll
    for (int t = 0; t < 4; ++t) acc[t] = bv;
    const float4* wr = (const float4*)(f2w + (size_t)o * HIDn);
    for (int kk = 0; kk < HIDn / 4; ++kk) {
        float4 w = wr[kk];
#pragma unroll
        for (int t = 0; t < 4; ++t) {
            float4 f = ((const float4*)&h1[tg * 4 + t][0])[kk];
            acc[t] += dot4(f, w);
        }
    }
#pragma unroll
    for (int t = 0; t < 4; ++t) z_e[(size_t)(tok0 + tg * 4 + t) * EMBn + o] = acc[t];
}

// ---------------------------------------------------------------- K3p: z -> bf16, per-token eps
__global__ __launch_bounds__(256) void k_zprep(const float* __restrict__ z_e,
                                               unsigned short* __restrict__ zbf,
                                               float* __restrict__ qtok) {
    const int lane = threadIdx.x & 63;
    const int tg = threadIdx.x >> 6;
    const int t = blockIdx.x * 4 + tg;
    float zv = z_e[(size_t)t * EMBn + lane];
    zbf[(size_t)t * EMBn + lane] = f2bf(zv);
    float s = zv * zv;
#pragma unroll
    for (int off = 32; off > 0; off >>= 1) s += __shfl_xor(s, off);
    if (lane == 0) qtok[t] = EPSC * sqrtf(s);
}

// ---------------------------------------------------------------- K3a: VQ sweep, barrier-free wave pipelines
__global__ __launch_bounds__(512, 4) void k_vq_sweep(
    const unsigned short* __restrict__ zbf, const unsigned short* __restrict__ cbbf,
    const float* __restrict__ e_sq, const float* __restrict__ qtok,
    const float* __restrict__ rcg,
    int* __restrict__ cntT, int* __restrict__ cand) {
    const int tid = threadIdx.x;
    const int lane = tid & 63;
    const int wid = tid >> 6;          // 0..7
    const int lrow = lane & 15;
    const int g = lane >> 4;           // 0..3
    const int tok0 = blockIdx.x * TOKB;

    __shared__ unsigned tauL[TOKB];    // running max-acc per token (encoded)
    __shared__ int cntL[TOKB];
    if (tid < TOKB) { tauL[tid] = 0u; cntL[tid] = 0; }

    short8v bz[2][2];
#pragma unroll
    for (int n = 0; n < 2; ++n)
#pragma unroll
        for (int kc = 0; kc < 2; ++kc)
            bz[n][kc] = *(const short8v*)(zbf + (size_t)(tok0 + n * 16 + lrow) * EMBn + kc * 32 + g * 8);
    float qn[2];
#pragma unroll
    for (int n = 0; n < 2; ++n) qn[n] = qtok[tok0 + n * 16 + lrow];
    const float rcm = rcg[0];
    __syncthreads(); // tauL/cntL init visible; ONLY barrier before the end

    for (int it = 0; it < NIT; ++it) {
        const int c0 = (it * 8 + wid) * KCW;   // this wave's 64 codes
        short8v ac[4][2];
        float4 e4[4];
#pragma unroll
        for (int m = 0; m < 4; ++m) {
#pragma unroll
            for (int kc = 0; kc < 2; ++kc)
                ac[m][kc] = *(const short8v*)(cbbf + (size_t)(c0 + m * 16 + lrow) * EMBn + kc * 32 + g * 8);
            e4[m] = *(const float4*)(e_sq + c0 + m * 16 + g * 4);
        }
        f32x4 acc[4][2];
#pragma unroll
        for (int m = 0; m < 4; ++m) {
            f32x4 em = {-0.5f * e4[m].x, -0.5f * e4[m].y, -0.5f * e4[m].z, -0.5f * e4[m].w};
            acc[m][0] = em;
            acc[m][1] = em;
        }
#pragma unroll
        for (int kc = 0; kc < 2; ++kc)
#pragma unroll
            for (int m = 0; m < 4; ++m)
#pragma unroll
                for (int n = 0; n < 2; ++n)
                    acc[m][n] = __builtin_amdgcn_mfma_f32_16x16x32_bf16(ac[m][kc], bz[n][kc], acc[m][n], 0, 0, 0);

#pragma unroll
        for (int n = 0; n < 2; ++n) {
            float v = acc[0][n][0];
#pragma unroll
            for (int m = 0; m < 4; ++m)
#pragma unroll
                for (int r = 0; r < 4; ++r) v = fmaxf(v, acc[m][n][r]);
            v = fmaxf(v, __shfl_xor(v, 16));
            v = fmaxf(v, __shfl_xor(v, 32));
            if (lane < 16) atomicMax(&tauL[n * 16 + lane], fenc(v));
            float tf = fmaxf(fdec(tauL[n * 16 + lrow]), v);
            float nthr = tf - qn[n] * rcm;
            const int tn = n * 16 + lrow;
#pragma unroll
            for (int m = 0; m < 4; ++m)
#pragma unroll
                for (int r = 0; r < 4; ++r)
                    if (acc[m][n][r] >= nthr) {
                        int slot = atomicAdd(&cntL[tn], 1);
                        if (slot < CAP)
                            cand[(size_t)(tok0 + tn) * CAP + slot] = c0 + m * 16 + g * 4 + r;
                    }
        }
    }
    __syncthreads();
    if (tid < TOKB) cntT[tok0 + tid] = cntL[tid];
}

// ---------------------------------------------------------------- K3b: exact f32 rescore of candidates (+ fallback)
__global__ __launch_bounds__(256) void k_vq_rescore(
    const int* __restrict__ cntT, const int* __restrict__ cand,
    const float* __restrict__ z_e, const float* __restrict__ cb,
    const float* __restrict__ e_sq,
    float* __restrict__ z_q, float* __restrict__ idx_out,
    int* __restrict__ counts, float* __restrict__ partials) {
    const int lane = threadIdx.x & 63;
    const int tg = threadIdx.x >> 6;
    const int t = blockIdx.x * 4 + tg;
    __shared__ float psum[4];

    float4 z[16];
    const float4* zr = (const float4*)(z_e + (size_t)t * EMBn);
#pragma unroll
    for (int q = 0; q < 16; ++q) z[q] = zr[q];

    const int n = cntT[t];
    float best = INFINITY;
    int bi = Kn;

    if (n > 0 && n <= CAP) {
        for (int s = lane; s < n; s += 64) {
            int c = cand[(size_t)t * CAP + s];
            const float4* cp = (const float4*)(cb + (size_t)c * EMBn);
            float a = 0.f;
#pragma unroll
            for (int q = 0; q < 16; ++q) a += dot4(z[q], cp[q]);
            float d = e_sq[c] - 2.f * a;
            if (d < best || (d == best && c < bi)) { best = d; bi = c; }
        }
    } else { // overflow (pathological) or empty: exact full scan
        for (int c0 = 0; c0 < Kn; c0 += 64) {
            int c = c0 + lane;
            const float4* cp = (const float4*)(cb + (size_t)c * EMBn);
            float a = 0.f;
#pragma unroll
            for (int q = 0; q < 16; ++q) a += dot4(z[q], cp[q]);
            float d = e_sq[c] - 2.f * a;
            if (d < best) { best = d; bi = c; } // ascending c per lane
        }
    }
#pragma unroll
    for (int off = 32; off > 0; off >>= 1) {
        float od = __shfl_xor(best, off);
        int oi = __shfl_xor(bi, off);
        if (od < best || (od == best && oi < bi)) { best = od; bi = oi; }
    }

    float cv = cb[(size_t)bi * EMBn + lane];
    z_q[(size_t)t * EMBn + lane] = cv;
    float zv = z_e[(size_t)t * EMBn + lane];
    float diff = zv - cv;
    float s = diff * diff;
#pragma unroll
    for (int off = 32; off > 0; off >>= 1) s += __shfl_xor(s, off);
    if (lane == 0) {
        psum[tg] = s;
        idx_out[t] = (float)bi;
        atomicAdd(&counts[bi], 1);
    }
    __syncthreads();
    if (threadIdx.x == 0) partials[blockIdx.x] = psum[0] + psum[1] + psum[2] + psum[3];
}

// ---------------------------------------------------------------- K4: backbone + small heads (+ h in bf16)
__global__ __launch_bounds__(256) void k_backbone(
    const float* __restrict__ z_q,
    const float* __restrict__ bb1w, const float* __restrict__ bb1b,
    const float* __restrict__ bb2w, const float* __restrict__ bb2b,
    const float* __restrict__ chw, const float* __restrict__ chb,
    const float* __restrict__ lcw, const float* __restrict__ lcb,
    float* __restrict__ h_out, unsigned short* __restrict__ hbf_out,
    float* __restrict__ cont_rec, float* __restrict__ lc_out) {
    const int tid = threadIdx.x;
    const int tok0 = blockIdx.x * 16;
    __shared__ float zq[16][68];
    __shared__ float h1[16][HIDn + 4];
    __shared__ float h2[16][HIDn + 4];
    {
        int t = tid >> 4, q = tid & 15;
        ((float4*)&zq[t][0])[q] = ((const float4*)(z_q + (size_t)(tok0 + t) * EMBn))[q];
    }
    __syncthreads();
    {
        int o = tid >> 1, half = tid & 1;
        float acc[8];
        float bv = bb1b[o];
#pragma unroll
        for (int t = 0; t < 8; ++t) acc[t] = bv;
        const float4* wr = (const float4*)(bb1w + (size_t)o * EMBn);
#pragma unroll
        for (int kk = 0; kk < 16; ++kk) {
            float4 w = wr[kk];
#pragma unroll
            for (int t = 0; t < 8; ++t) acc[t] += dot4(((const float4*)&zq[half * 8 + t][0])[kk], w);
        }
#pragma unroll
        for (int t = 0; t < 8; ++t) h1[half * 8 + t][o] = fmaxf(acc[t], 0.f);
    }
    __syncthreads();
    {
        int o = tid >> 1, half = tid & 1;
        float acc[8];
        float bv = bb2b[o];
#pragma unroll
        for (int t = 0; t < 8; ++t) acc[t] = bv;
        const float4* wr = (const float4*)(bb2w + (size_t)o * HIDn);
        for (int kk = 0; kk < 32; ++kk) {
            float4 w = wr[kk];
#pragma unroll
            for (int t = 0; t < 8; ++t) acc[t] += dot4(((const float4*)&h1[half * 8 + t][0])[kk], w);
        }
#pragma unroll
        for (int t = 0; t < 8; ++t) {
            float v = fmaxf(acc[t], 0.f);
            h2[half * 8 + t][o] = v;
            h_out[(size_t)(tok0 + half * 8 + t) * HIDn + o] = v;
            hbf_out[(size_t)(tok0 + half * 8 + t) * HIDn + o] = f2bf(v);
        }
    }
    __syncthreads();
    {
        int t = tid >> 4, o = tid & 15;
        float a = chb[o];
        const float4* wr = (const float4*)(chw + (size_t)o * HIDn);
#pragma unroll
        for (int kk = 0; kk < 32; ++kk) a += dot4(((const float4*)&h2[t][0])[kk], wr[kk]);
        cont_rec[(size_t)(tok0 + t) * CONTn + o] = a;
    }
    for (int idx = tid; idx < 16 * 32; idx += 256) {
        int t = idx >> 5, o = idx & 31;
        float a = lcb[o];
        const float4* wr = (const float4*)(lcw + (size_t)o * HIDn);
#pragma unroll
        for (int kk = 0; kk < 32; ++kk) a += dot4(((const float4*)&h2[t][0])[kk], wr[kk]);
        lc_out[(size_t)(tok0 + t) * VLCn + o] = a;
    }
}

// ---------------------------------------------------------------- K5: sp_logits via bf16 MFMA, direct-from-L2 frags
__global__ __launch_bounds__(256, 3) void k_sp_mfma(
    const unsigned short* __restrict__ hbf, const unsigned short* __restrict__ wbf,
    const float* __restrict__ bias, float* __restrict__ out) {
    const int tid = threadIdx.x;
    const int lane = tid & 63;
    const int wid = tid >> 6;
    const int tok_w = blockIdx.y * 128 + (wid & 1) * 64;
    const int v_w = blockIdx.x * 128 + (wid >> 1) * 64;

    const int lrow = lane & 15;
    const int lk = (lane >> 4) * 8;

    const unsigned short* ha = hbf + (size_t)(tok_w + lrow) * HIDn + lk;
    const unsigned short* wa = wbf + (size_t)(v_w + lrow) * HIDn + lk;

    f32x4 acc[4][4];
#pragma unroll
    for (int m = 0; m < 4; ++m)
#pragma unroll
        for (int n = 0; n < 4; ++n) acc[m][n] = (f32x4){0.f, 0.f, 0.f, 0.f};

#pragma unroll
    for (int ks = 0; ks < 4; ++ks) {
        const int kk = ks * 32;
        short8v a[4], b[4];
#pragma unroll
        for (int m = 0; m < 4; ++m)
            a[m] = *(const short8v*)(ha + (size_t)m * 16 * HIDn + kk);
#pragma unroll
        for (int n = 0; n < 4; ++n)
            b[n] = *(const short8v*)(wa + (size_t)n * 16 * HIDn + kk);
#pragma unroll
        for (int m = 0; m < 4; ++m)
#pragma unroll
            for (int n = 0; n < 4; ++n)
                acc[m][n] = __builtin_amdgcn_mfma_f32_16x16x32_bf16(a[m], b[n], acc[m][n], 0, 0, 0);
    }

    const int r0 = (lane >> 4) * 4;
#pragma unroll
    for (int n = 0; n < 4; ++n) {
        const int col = v_w + n * 16 + lrow;
        if (col < VSPn) {
            const float bv = bias[col];
#pragma unroll
            for (int m = 0; m < 4; ++m) {
                const int row = tok_w + m * 16 + r0;
#pragma unroll
                for (int r = 0; r < 4; ++r)
                    out[(size_t)(row + r) * VSPn + col] = acc[m][n][r] + bv;
            }
        }
    }
}

// ---------------------------------------------------------------- K6: canopy head on h[:, -1, :]
__global__ __launch_bounds__(128) void k_canopy(const float* __restrict__ h,
                                                const float* __restrict__ w1,
                                                const float* __restrict__ b1,
                                                const float* __restrict__ w2,
                                                const float* __restrict__ b2,
                                                float* __restrict__ can) {
    int b = blockIdx.x, o = threadIdx.x;
    __shared__ float r[128];
    const float4* hr = (const float4*)(h + (size_t)(b * Tn + Tn - 1) * HIDn);
    const float4* wr = (const float4*)(w1 + (size_t)o * HIDn);
    float a = b1[o];
#pragma unroll
    for (int kk = 0; kk < 32; ++kk) a += dot4(hr[kk], wr[kk]);
    r[o] = fmaxf(a, 0.f) * w2[o];
    __syncthreads();
    for (int s = 64; s > 0; s >>= 1) {
        if (o < s) r[o] += r[o + s];
        __syncthreads();
    }
    if (o == 0) can[b] = r[0] + b2[0];
}

// ---------------------------------------------------------------- K7: loss + perplexity
__global__ __launch_bounds__(256) void k_finalize(const float* __restrict__ partials,
                                                  const int* __restrict__ counts,
                                                  float* __restrict__ out_loss,
                                                  float* __restrict__ out_ppl) {
    const int tid = threadIdx.x;
    __shared__ float red[256];
    float ps = 0.f;
#pragma unroll
    for (int j = 0; j < (BTn / 4) / 256; ++j) ps += partials[tid * ((BTn / 4) / 256) + j];
    red[tid] = ps;
    __syncthreads();
    for (int s = 128; s > 0; s >>= 1) {
        if (tid < s) red[tid] += red[tid + s];
        __syncthreads();
    }
    float total = red[0];
    __syncthreads();
    float e = 0.f;
    for (int i = tid; i < Kn; i += 256) {
        float p = (float)counts[i] * (1.0f / BTn);
        e += p * logf(p + 1e-12f);
    }
    red[tid] = e;
    __syncthreads();
    for (int s = 128; s > 0; s >>= 1) {
        if (tid < s) red[tid] += red[tid + s];
        __syncthreads();
    }
    if (tid == 0) {
        out_loss[0] = 1.25f * total / (float)((size_t)BTn * EMBn);
        out_ppl[0] = expf(-red[0]);
    }
}

// ----------------------------------------------------------------
extern "C" void kernel_launch(void* const* d_in, const int* in_sizes, int n_in,
                              void* d_out, int out_size, void* d_ws, size_t ws_size,
                              hipStream_t stream) {
    const float* cont = (const float*)d_in[0];
    const float* naip = (const float*)d_in[1];
    const int* cat = (const int*)d_in[2];
    const float* emb_sp = (const float*)d_in[3];
    const float* emb_lc = (const float*)d_in[4];
    const float* conv_w = (const float*)d_in[5];
    const float* conv_b = (const float*)d_in[6];
    const float* npw = (const float*)d_in[7];
    const float* npb = (const float*)d_in[8];
    const float* cpw = (const float*)d_in[9];
    const float* cpb = (const float*)d_in[10];
    const float* caw = (const float*)d_in[11];
    const float* cab = (const float*)d_in[12];
    const float* f1w = (const float*)d_in[13];
    const float* f1b = (const float*)d_in[14];
    const float* f2w = (const float*)d_in[15];
    const float* f2b = (const float*)d_in[16];
    const float* cb = (const float*)d_in[17];
    const float* bb1w = (const float*)d_in[18];
    const float* bb1b = (const float*)d_in[19];
    const float* bb2w = (const float*)d_in[20];
    const float* bb2b = (const float*)d_in[21];
    const float* chw = (const float*)d_in[22];
    const float* chb = (const float*)d_in[23];
    const float* spw = (const float*)d_in[24];
    const float* spb = (const float*)d_in[25];
    const float* lcw = (const float*)d_in[26];
    const float* lcb = (const float*)d_in[27];
    const float* c1w = (const float*)d_in[28];
    const float* c1b = (const float*)d_in[29];
    const float* c2w = (const float*)d_in[30];
    const float* c2b = (const float*)d_in[31];

    float* out = (float*)d_out;
    float* ws = (float*)d_ws;
    float* naip2 = ws + WS_NAIP2;
    float* z_e = ws + WS_ZE;
    float* z_q = ws + WS_ZQ;
    float* h = ws + WS_H;
    float* e_sq = ws + WS_ESQ;
    float* parts = ws + WS_PART;
    int* counts = (int*)(ws + WS_CNTK);
    int* cntT = (int*)(ws + WS_CNTT);
    float* qtok = ws + WS_Q;
    int* cand = (int*)(ws + WS_CAND);
    unsigned short* zbf = (unsigned short*)(ws + WS_ZBF);
    unsigned short* cbbf = (unsigned short*)(ws + WS_CBBF);
    unsigned short* hbf = (unsigned short*)(ws + WS_HBF);
    unsigned short* wbf = (unsigned short*)(ws + WS_WBF);
    float* rcg = ws + WS_RCG;
    float* fused_g = ws + WS_FUSED;
    float* h1g = ws + WS_H1;

    k_esq_zero<<<dim3(Kn / 256), dim3(256), 0, stream>>>(cb, e_sq, counts, cbbf);
    k_rcmax<<<dim3(1), dim3(256), 0, stream>>>(e_sq, rcg);
    k_wcast<<<dim3(VSP_PAD * HIDn / 4 / 256), dim3(256), 0, stream>>>(spw, wbf);
    k_naip<<<dim3(Bn), dim3(128), 0, stream>>>(naip, conv_w, conv_b, npw, npb, naip2);
    k_fused<<<dim3(BTn / 64), dim3(256), 0, stream>>>(cont, cat, emb_sp, emb_lc, cpw, cpb,
                                                      caw, cab, naip2, fused_g);
    k_f1<<<dim3(BTn / 64), dim3(256), 0, stream>>>(fused_g, f1w, f1b, h1g);
    k_f2<<<dim3(BTn / 16), dim3(256), 0, stream>>>(h1g, f2w, f2b, z_e);
    k_zprep<<<dim3(BTn / 4), dim3(256), 0, stream>>>(z_e, zbf, qtok);
    k_vq_sweep<<<dim3(BTn / TOKB), dim3(512), 0, stream>>>(zbf, cbbf, e_sq, qtok, rcg, cntT, cand);
    k_vq_rescore<<<dim3(BTn / 4), dim3(256), 0, stream>>>(cntT, cand, z_e, cb, e_sq, z_q,
                                                          out + O_IDX, counts, parts);
    k_backbone<<<dim3(BTn / 16), dim3(256), 0, stream>>>(z_q, bb1w, bb1b, bb2w, bb2b, chw, chb,
                                                         lcw, lcb, h, hbf, out + O_CONT, out + O_LC);
    k_sp_mfma<<<dim3(VSP_PAD / 128, BTn / 128), dim3(256), 0, stream>>>(hbf, wbf, spb, out + O_SP);
    k_canopy<<<dim3(Bn), dim3(128), 0, stream>>>(h, c1w, c1b, c2w, c2b, out + O_CAN);
    k_finalize<<<dim3(1), dim3(256), 0, stream>>>(parts, counts, out + O_LOSS, out + O_PPL);
}

// Round 14
// 503.633 us; speedup vs baseline: 1.4292x; 1.4292x over previous
//
#include <hip/hip_runtime.h>
#include <cmath>

namespace {
constexpr int Bn = 128, Tn = 128, BTn = Bn * Tn;
constexpr int CONTn = 16, HIDn = 128, EMBn = 64;
constexpr int Kn = 8192, CEn = 6, VSPn = 2000, VLCn = 32, FINn = 3 * HIDn;
constexpr int VSP_PAD = 2048;             // padded vocab for MFMA tiles
constexpr int CAP = 128;                  // max stored VQ candidates per token
constexpr float EPSC = 0.02f;             // rigorous bf16 interval coeff (2^-6 * 1.28)
constexpr int TOKB = 32;                  // tokens per sweep block
constexpr int KCW = 64;                   // codes per wave-chunk
constexpr int NIT = Kn / (KCW * 8);       // 16 chunk-iterations per wave (8 waves)

// ---- workspace layout (float units) ----
constexpr size_t WS_NAIP2 = 0;                               // B*HID
constexpr size_t WS_ZE    = WS_NAIP2 + (size_t)Bn * HIDn;    // BT*EMB
constexpr size_t WS_ZQ    = WS_ZE + (size_t)BTn * EMBn;      // BT*EMB
constexpr size_t WS_H     = WS_ZQ + (size_t)BTn * EMBn;      // BT*HID
constexpr size_t WS_ESQ   = WS_H + (size_t)BTn * HIDn;       // K
constexpr size_t WS_PART  = WS_ESQ + Kn;                     // BT/4 partial loss sums
constexpr size_t WS_CNTK  = WS_PART + BTn / 4;               // K ints (code counts)
constexpr size_t WS_CNTT  = WS_CNTK + Kn;                    // BT ints (candidate counts)
constexpr size_t WS_Q     = WS_CNTT + BTn;                   // BT floats (eps per token)
constexpr size_t WS_CAND  = WS_Q + BTn;                      // BT*CAP ints
constexpr size_t WS_ZBF   = WS_CAND + (size_t)BTn * CAP;     // BT*EMB ushort
constexpr size_t WS_CBBF  = WS_ZBF + (size_t)BTn * EMBn / 2; // K*EMB ushort
constexpr size_t WS_HBF   = WS_CBBF + (size_t)Kn * EMBn / 2; // BT*HID ushort
constexpr size_t WS_WBF   = WS_HBF + (size_t)BTn * HIDn / 2; // VSP_PAD*HID ushort
constexpr size_t WS_RCG   = WS_WBF + (size_t)VSP_PAD * HIDn / 2; // 1 float (global rcmax)
constexpr size_t WS_FUSED = WS_RCG + 1;                      // BT*FIN floats
constexpr size_t WS_H1    = WS_FUSED + (size_t)BTn * FINn;   // BT*HID floats

// ---- output layout (float units) ----
constexpr size_t O_CONT = 0;
constexpr size_t O_SP   = O_CONT + (size_t)BTn * CONTn;
constexpr size_t O_LC   = O_SP + (size_t)BTn * VSPn;
constexpr size_t O_CAN  = O_LC + (size_t)BTn * VLCn;
constexpr size_t O_IDX  = O_CAN + Bn;
constexpr size_t O_LOSS = O_IDX + BTn;
constexpr size_t O_PPL  = O_LOSS + 1;
} // namespace

typedef __attribute__((ext_vector_type(8))) short short8v;  // 8 bf16 = 4 VGPR
typedef __attribute__((ext_vector_type(4))) float f32x4;

__device__ __forceinline__ float nan0(float v) {
    return __builtin_isfinite(v) ? v : 0.0f;
}
__device__ __forceinline__ float dot4(float4 a, float4 b) {
    return a.x * b.x + a.y * b.y + a.z * b.z + a.w * b.w;
}
__device__ __forceinline__ unsigned short f2bf(float f) { // RNE, finite-only
    union { float f; unsigned u; } v{f};
    unsigned r = v.u + 0x7FFFu + ((v.u >> 16) & 1u);
    return (unsigned short)(r >> 16);
}
// monotone float<->uint encoding (for atomicMax on floats of any sign)
__device__ __forceinline__ unsigned fenc(float f) {
    unsigned b = __float_as_uint(f);
    return (b & 0x80000000u) ? ~b : (b | 0x80000000u);
}
__device__ __forceinline__ float fdec(unsigned k) {
    unsigned b = (k >> 31) ? (k & 0x7fffffffu) : ~k;
    return __uint_as_float(b);
}

// ---------------------------------------------------------------- K0: zero code counts + e_sq + bf16 codebook
__global__ __launch_bounds__(256) void k_esq_zero(const float* __restrict__ cb,
                                                  float* __restrict__ e_sq,
                                                  int* __restrict__ counts,
                                                  unsigned short* __restrict__ cbbf) {
    int i = blockIdx.x * 256 + threadIdx.x;
    if (i < Kn) {
        counts[i] = 0;
        const float4* r = (const float4*)(cb + (size_t)i * EMBn);
        float s = 0.f;
#pragma unroll
        for (int j = 0; j < 16; ++j) {
            float4 v = r[j];
            s += dot4(v, v);
            unsigned short u[4] = {f2bf(v.x), f2bf(v.y), f2bf(v.z), f2bf(v.w)};
            *(uint2*)(cbbf + (size_t)i * EMBn + j * 4) = *(const uint2*)u;
        }
        e_sq[i] = s;
    }
}

// ---------------------------------------------------------------- K0c: global max codebook norm
__global__ __launch_bounds__(256) void k_rcmax(const float* __restrict__ e_sq,
                                               float* __restrict__ rcg) {
    const int tid = threadIdx.x;
    float m = 0.f;
#pragma unroll
    for (int j = 0; j < Kn / 256; ++j) m = fmaxf(m, e_sq[j * 256 + tid]);
#pragma unroll
    for (int off = 32; off > 0; off >>= 1) m = fmaxf(m, __shfl_xor(m, off));
    __shared__ float wm[4];
    if ((tid & 63) == 0) wm[tid >> 6] = m;
    __syncthreads();
    if (tid == 0)
        rcg[0] = sqrtf(fmaxf(fmaxf(wm[0], wm[1]), fmaxf(wm[2], wm[3]))) * 1.000001f;
}

// ---------------------------------------------------------------- K0b: sp_head_w -> bf16, padded to 2048 rows
__global__ __launch_bounds__(256) void k_wcast(const float* __restrict__ w,
                                               unsigned short* __restrict__ wbf) {
    int i = blockIdx.x * 256 + threadIdx.x;      // float4 index; 32 per row
    int v = i >> 5;
    unsigned short u[4] = {0, 0, 0, 0};
    if (v < VSPn) {
        float4 x = ((const float4*)w)[i];
        u[0] = f2bf(x.x); u[1] = f2bf(x.y); u[2] = f2bf(x.z); u[3] = f2bf(x.w);
    }
    *(uint2*)(wbf + (size_t)i * 4) = *(const uint2*)u;
}

// ---------------------------------------------------------------- K1: naip conv + proj -> naip2 (B x HID)
__global__ __launch_bounds__(128) void k_naip(const float* __restrict__ naip,
                                              const float* __restrict__ conv_w,
                                              const float* __restrict__ conv_b,
                                              const float* __restrict__ pw,
                                              const float* __restrict__ pb,
                                              float* __restrict__ naip2) {
    int b = blockIdx.x, o = threadIdx.x;
    __shared__ float feat[HIDn];
    float acc = conv_b[o];
#pragma unroll
    for (int i = 0; i < 9; ++i) acc += nan0(naip[b * 9 + i]) * conv_w[o * 9 + i];
    feat[o] = fmaxf(acc, 0.f);
    __syncthreads();
    float a2 = pb[o];
    const float4* wr = (const float4*)(pw + (size_t)o * HIDn);
    const float4* fr = (const float4*)feat;
#pragma unroll
    for (int j = 0; j < 32; ++j) a2 += dot4(fr[j], wr[j]);
    naip2[(size_t)b * HIDn + o] = a2;
}

// ---------------------------------------------------------------- K2a: build fused[BT][384] (bit-identical formulas)
__global__ __launch_bounds__(256) void k_fused(
    const float* __restrict__ cont, const int* __restrict__ cat,
    const float* __restrict__ emb_sp, const float* __restrict__ emb_lc,
    const float* __restrict__ cpw, const float* __restrict__ cpb,
    const float* __restrict__ caw, const float* __restrict__ cab,
    const float* __restrict__ naip2, float* __restrict__ fused_g) {
    const int tok0 = blockIdx.x * 64;
    const int tid = threadIdx.x;
    // sec0: naip broadcast
    for (int idx = tid; idx < 64 * HIDn; idx += 256) {
        int t = idx >> 7, j = idx & 127;
        int tok = tok0 + t;
        fused_g[(size_t)tok * FINn + j] = naip2[(size_t)(tok >> 7) * HIDn + j];
    }
    // sec1: cont projection
    for (int idx = tid; idx < 64 * HIDn; idx += 256) {
        int t = idx >> 7, o = idx & 127;
        int tok = tok0 + t;
        const float4* cp = (const float4*)(cont + (size_t)tok * CONTn);
        const float4* wr = (const float4*)(cpw + (size_t)o * CONTn);
        float a = cpb[o];
#pragma unroll
        for (int q = 0; q < 4; ++q) {
            float4 c4 = cp[q], w4 = wr[q];
            a += nan0(c4.x) * w4.x + nan0(c4.y) * w4.y + nan0(c4.z) * w4.z + nan0(c4.w) * w4.w;
        }
        fused_g[(size_t)tok * FINn + HIDn + o] = a;
    }
    // sec2: cat embedding projection
    for (int idx = tid; idx < 64 * HIDn; idx += 256) {
        int t = idx >> 7, o = idx & 127;
        int tok = tok0 + t;
        int c0 = cat[tok * 2], c1 = cat[tok * 2 + 1];
        const float* e0 = emb_sp + (size_t)c0 * CEn;
        const float* e1 = emb_lc + (size_t)c1 * CEn;
        const float* wr = caw + (size_t)o * (2 * CEn);
        float a = cab[o];
#pragma unroll
        for (int i = 0; i < CEn; ++i) a += e0[i] * wr[i];
#pragma unroll
        for (int i = 0; i < CEn; ++i) a += e1[i] * wr[CEn + i];
        fused_g[(size_t)tok * FINn + 2 * HIDn + o] = a;
    }
}

// ---------------------------------------------------------------- K2b: fuse1 GEMM (64-tok x 128-out tile, f32, swizzled LDS)
// grid BTn/64; 256 threads; per-thread 4 toks x 8 outs; K=384 in 12 slices of 32.
// acc init = f1b; kk ascending => h1 chain identical to round-12 k_ze phase B.
// Round-13 post-mortem: __launch_bounds__(256,4) capped VGPR at 64 -> accumulator
// spilled to scratch (FETCH 372 MB, WRITE 652 MB). Fix: (256,2) (proven in r3's
// k_vq_partial: VGPR 100, no spill) + load ww per-j instead of caching ww[8]
// (peak live ~60 regs).
__global__ __launch_bounds__(256, 2) void k_f1(const float* __restrict__ fused_g,
                                               const float* __restrict__ f1w,
                                               const float* __restrict__ f1b,
                                               float* __restrict__ h1g) {
    const int tid = threadIdx.x;
    const int x = tid & 15, y = tid >> 4;
    const int tok0 = blockIdx.x * 64;
    __shared__ __align__(16) float ht[64 * 32];
    __shared__ __align__(16) float wt[128 * 32];

    float acc[4][8];
#pragma unroll
    for (int j = 0; j < 8; ++j) {
        float bv = f1b[x + 16 * j];
#pragma unroll
        for (int t = 0; t < 4; ++t) acc[t][j] = bv;
    }

    for (int s = 0; s < 12; ++s) {
        __syncthreads();
#pragma unroll
        for (int w = 0; w < 2; ++w) {
            int idx = tid + w * 256;
            int row = idx >> 3, c4 = idx & 7;
            float4 v = *(const float4*)(fused_g + (size_t)(tok0 + row) * FINn + s * 32 + c4 * 4);
            ((float4*)ht)[row * 8 + (c4 ^ ((row >> 2) & 3))] = v;
        }
#pragma unroll
        for (int w = 0; w < 4; ++w) {
            int idx = tid + w * 256;
            int row = idx >> 3, c4 = idx & 7;
            float4 v = *(const float4*)(f1w + (size_t)row * FINn + s * 32 + c4 * 4);
            ((float4*)wt)[row * 8 + (c4 ^ (row & 7))] = v;
        }
        __syncthreads();
#pragma unroll
        for (int kk = 0; kk < 8; ++kk) {
            float4 hh[4];
#pragma unroll
            for (int t = 0; t < 4; ++t) {
                int row = y * 4 + t;
                hh[t] = ((const float4*)ht)[row * 8 + (kk ^ ((row >> 2) & 3))];
            }
#pragma unroll
            for (int j = 0; j < 8; ++j) {
                int row = x + 16 * j;
                float4 ww = ((const float4*)wt)[row * 8 + (kk ^ (row & 7))];
#pragma unroll
                for (int t = 0; t < 4; ++t) acc[t][j] += dot4(hh[t], ww);
            }
        }
    }
#pragma unroll
    for (int t = 0; t < 4; ++t)
#pragma unroll
        for (int j = 0; j < 8; ++j)
            h1g[(size_t)(tok0 + y * 4 + t) * HIDn + x + 16 * j] = fmaxf(acc[t][j], 0.f);
}

// ---------------------------------------------------------------- K2c: z_e = h1 @ f2w^T + b (verbatim original C-phase)
__global__ __launch_bounds__(256) void k_f2(const float* __restrict__ h1g,
                                            const float* __restrict__ f2w,
                                            const float* __restrict__ f2b,
                                            float* __restrict__ z_e) {
    const int tok0 = blockIdx.x * 16;
    const int tid = threadIdx.x;
    __shared__ float h1[16][HIDn + 4];
    for (int idx = tid; idx < 16 * 32; idx += 256) {
        int t = idx >> 5, q = idx & 31;
        ((float4*)&h1[t][0])[q] = ((const float4*)(h1g + (size_t)(tok0 + t) * HIDn))[q];
    }
    __syncthreads();
    int o = tid & 63, tg = tid >> 6;
    float acc[4];
    float bv = f2b[o];
#pragma unroll
    for (int t = 0; t < 4; ++t) acc[t] = bv;
    const float4* wr = (const float4*)(f2w + (size_t)o * HIDn);
    for (int kk = 0; kk < HIDn / 4; ++kk) {
        float4 w = wr[kk];
#pragma unroll
        for (int t = 0; t < 4; ++t) {
            float4 f = ((const float4*)&h1[tg * 4 + t][0])[kk];
            acc[t] += dot4(f, w);
        }
    }
#pragma unroll
    for (int t = 0; t < 4; ++t) z_e[(size_t)(tok0 + tg * 4 + t) * EMBn + o] = acc[t];
}

// ---------------------------------------------------------------- K3p: z -> bf16, per-token eps
__global__ __launch_bounds__(256) void k_zprep(const float* __restrict__ z_e,
                                               unsigned short* __restrict__ zbf,
                                               float* __restrict__ qtok) {
    const int lane = threadIdx.x & 63;
    const int tg = threadIdx.x >> 6;
    const int t = blockIdx.x * 4 + tg;
    float zv = z_e[(size_t)t * EMBn + lane];
    zbf[(size_t)t * EMBn + lane] = f2bf(zv);
    float s = zv * zv;
#pragma unroll
    for (int off = 32; off > 0; off >>= 1) s += __shfl_xor(s, off);
    if (lane == 0) qtok[t] = EPSC * sqrtf(s);
}

// ---------------------------------------------------------------- K3a: VQ sweep, barrier-free wave pipelines
__global__ __launch_bounds__(512, 4) void k_vq_sweep(
    const unsigned short* __restrict__ zbf, const unsigned short* __restrict__ cbbf,
    const float* __restrict__ e_sq, const float* __restrict__ qtok,
    const float* __restrict__ rcg,
    int* __restrict__ cntT, int* __restrict__ cand) {
    const int tid = threadIdx.x;
    const int lane = tid & 63;
    const int wid = tid >> 6;          // 0..7
    const int lrow = lane & 15;
    const int g = lane >> 4;           // 0..3
    const int tok0 = blockIdx.x * TOKB;

    __shared__ unsigned tauL[TOKB];    // running max-acc per token (encoded)
    __shared__ int cntL[TOKB];
    if (tid < TOKB) { tauL[tid] = 0u; cntL[tid] = 0; }

    short8v bz[2][2];
#pragma unroll
    for (int n = 0; n < 2; ++n)
#pragma unroll
        for (int kc = 0; kc < 2; ++kc)
            bz[n][kc] = *(const short8v*)(zbf + (size_t)(tok0 + n * 16 + lrow) * EMBn + kc * 32 + g * 8);
    float qn[2];
#pragma unroll
    for (int n = 0; n < 2; ++n) qn[n] = qtok[tok0 + n * 16 + lrow];
    const float rcm = rcg[0];
    __syncthreads(); // tauL/cntL init visible; ONLY barrier before the end

    for (int it = 0; it < NIT; ++it) {
        const int c0 = (it * 8 + wid) * KCW;   // this wave's 64 codes
        short8v ac[4][2];
        float4 e4[4];
#pragma unroll
        for (int m = 0; m < 4; ++m) {
#pragma unroll
            for (int kc = 0; kc < 2; ++kc)
                ac[m][kc] = *(const short8v*)(cbbf + (size_t)(c0 + m * 16 + lrow) * EMBn + kc * 32 + g * 8);
            e4[m] = *(const float4*)(e_sq + c0 + m * 16 + g * 4);
        }
        f32x4 acc[4][2];
#pragma unroll
        for (int m = 0; m < 4; ++m) {
            f32x4 em = {-0.5f * e4[m].x, -0.5f * e4[m].y, -0.5f * e4[m].z, -0.5f * e4[m].w};
            acc[m][0] = em;
            acc[m][1] = em;
        }
#pragma unroll
        for (int kc = 0; kc < 2; ++kc)
#pragma unroll
            for (int m = 0; m < 4; ++m)
#pragma unroll
                for (int n = 0; n < 2; ++n)
                    acc[m][n] = __builtin_amdgcn_mfma_f32_16x16x32_bf16(ac[m][kc], bz[n][kc], acc[m][n], 0, 0, 0);

#pragma unroll
        for (int n = 0; n < 2; ++n) {
            float v = acc[0][n][0];
#pragma unroll
            for (int m = 0; m < 4; ++m)
#pragma unroll
                for (int r = 0; r < 4; ++r) v = fmaxf(v, acc[m][n][r]);
            v = fmaxf(v, __shfl_xor(v, 16));
            v = fmaxf(v, __shfl_xor(v, 32));
            if (lane < 16) atomicMax(&tauL[n * 16 + lane], fenc(v));
            float tf = fmaxf(fdec(tauL[n * 16 + lrow]), v);
            float nthr = tf - qn[n] * rcm;
            const int tn = n * 16 + lrow;
#pragma unroll
            for (int m = 0; m < 4; ++m)
#pragma unroll
                for (int r = 0; r < 4; ++r)
                    if (acc[m][n][r] >= nthr) {
                        int slot = atomicAdd(&cntL[tn], 1);
                        if (slot < CAP)
                            cand[(size_t)(tok0 + tn) * CAP + slot] = c0 + m * 16 + g * 4 + r;
                    }
        }
    }
    __syncthreads();
    if (tid < TOKB) cntT[tok0 + tid] = cntL[tid];
}

// ---------------------------------------------------------------- K3b: exact f32 rescore of candidates (+ fallback)
__global__ __launch_bounds__(256) void k_vq_rescore(
    const int* __restrict__ cntT, const int* __restrict__ cand,
    const float* __restrict__ z_e, const float* __restrict__ cb,
    const float* __restrict__ e_sq,
    float* __restrict__ z_q, float* __restrict__ idx_out,
    int* __restrict__ counts, float* __restrict__ partials) {
    const int lane = threadIdx.x & 63;
    const int tg = threadIdx.x >> 6;
    const int t = blockIdx.x * 4 + tg;
    __shared__ float psum[4];

    float4 z[16];
    const float4* zr = (const float4*)(z_e + (size_t)t * EMBn);
#pragma unroll
    for (int q = 0; q < 16; ++q) z[q] = zr[q];

    const int n = cntT[t];
    float best = INFINITY;
    int bi = Kn;

    if (n > 0 && n <= CAP) {
        for (int s = lane; s < n; s += 64) {
            int c = cand[(size_t)t * CAP + s];
            const float4* cp = (const float4*)(cb + (size_t)c * EMBn);
            float a = 0.f;
#pragma unroll
            for (int q = 0; q < 16; ++q) a += dot4(z[q], cp[q]);
            float d = e_sq[c] - 2.f * a;
            if (d < best || (d == best && c < bi)) { best = d; bi = c; }
        }
    } else { // overflow (pathological) or empty: exact full scan
        for (int c0 = 0; c0 < Kn; c0 += 64) {
            int c = c0 + lane;
            const float4* cp = (const float4*)(cb + (size_t)c * EMBn);
            float a = 0.f;
#pragma unroll
            for (int q = 0; q < 16; ++q) a += dot4(z[q], cp[q]);
            float d = e_sq[c] - 2.f * a;
            if (d < best) { best = d; bi = c; } // ascending c per lane
        }
    }
#pragma unroll
    for (int off = 32; off > 0; off >>= 1) {
        float od = __shfl_xor(best, off);
        int oi = __shfl_xor(bi, off);
        if (od < best || (od == best && oi < bi)) { best = od; bi = oi; }
    }

    float cv = cb[(size_t)bi * EMBn + lane];
    z_q[(size_t)t * EMBn + lane] = cv;
    float zv = z_e[(size_t)t * EMBn + lane];
    float diff = zv - cv;
    float s = diff * diff;
#pragma unroll
    for (int off = 32; off > 0; off >>= 1) s += __shfl_xor(s, off);
    if (lane == 0) {
        psum[tg] = s;
        idx_out[t] = (float)bi;
        atomicAdd(&counts[bi], 1);
    }
    __syncthreads();
    if (threadIdx.x == 0) partials[blockIdx.x] = psum[0] + psum[1] + psum[2] + psum[3];
}

// ---------------------------------------------------------------- K4: backbone + small heads (+ h in bf16)
__global__ __launch_bounds__(256) void k_backbone(
    const float* __restrict__ z_q,
    const float* __restrict__ bb1w, const float* __restrict__ bb1b,
    const float* __restrict__ bb2w, const float* __restrict__ bb2b,
    const float* __restrict__ chw, const float* __restrict__ chb,
    const float* __restrict__ lcw, const float* __restrict__ lcb,
    float* __restrict__ h_out, unsigned short* __restrict__ hbf_out,
    float* __restrict__ cont_rec, float* __restrict__ lc_out) {
    const int tid = threadIdx.x;
    const int tok0 = blockIdx.x * 16;
    __shared__ float zq[16][68];
    __shared__ float h1[16][HIDn + 4];
    __shared__ float h2[16][HIDn + 4];
    {
        int t = tid >> 4, q = tid & 15;
        ((float4*)&zq[t][0])[q] = ((const float4*)(z_q + (size_t)(tok0 + t) * EMBn))[q];
    }
    __syncthreads();
    {
        int o = tid >> 1, half = tid & 1;
        float acc[8];
        float bv = bb1b[o];
#pragma unroll
        for (int t = 0; t < 8; ++t) acc[t] = bv;
        const float4* wr = (const float4*)(bb1w + (size_t)o * EMBn);
#pragma unroll
        for (int kk = 0; kk < 16; ++kk) {
            float4 w = wr[kk];
#pragma unroll
            for (int t = 0; t < 8; ++t) acc[t] += dot4(((const float4*)&zq[half * 8 + t][0])[kk], w);
        }
#pragma unroll
        for (int t = 0; t < 8; ++t) h1[half * 8 + t][o] = fmaxf(acc[t], 0.f);
    }
    __syncthreads();
    {
        int o = tid >> 1, half = tid & 1;
        float acc[8];
        float bv = bb2b[o];
#pragma unroll
        for (int t = 0; t < 8; ++t) acc[t] = bv;
        const float4* wr = (const float4*)(bb2w + (size_t)o * HIDn);
        for (int kk = 0; kk < 32; ++kk) {
            float4 w = wr[kk];
#pragma unroll
            for (int t = 0; t < 8; ++t) acc[t] += dot4(((const float4*)&h1[half * 8 + t][0])[kk], w);
        }
#pragma unroll
        for (int t = 0; t < 8; ++t) {
            float v = fmaxf(acc[t], 0.f);
            h2[half * 8 + t][o] = v;
            h_out[(size_t)(tok0 + half * 8 + t) * HIDn + o] = v;
            hbf_out[(size_t)(tok0 + half * 8 + t) * HIDn + o] = f2bf(v);
        }
    }
    __syncthreads();
    {
        int t = tid >> 4, o = tid & 15;
        float a = chb[o];
        const float4* wr = (const float4*)(chw + (size_t)o * HIDn);
#pragma unroll
        for (int kk = 0; kk < 32; ++kk) a += dot4(((const float4*)&h2[t][0])[kk], wr[kk]);
        cont_rec[(size_t)(tok0 + t) * CONTn + o] = a;
    }
    for (int idx = tid; idx < 16 * 32; idx += 256) {
        int t = idx >> 5, o = idx & 31;
        float a = lcb[o];
        const float4* wr = (const float4*)(lcw + (size_t)o * HIDn);
#pragma unroll
        for (int kk = 0; kk < 32; ++kk) a += dot4(((const float4*)&h2[t][0])[kk], wr[kk]);
        lc_out[(size_t)(tok0 + t) * VLCn + o] = a;
    }
}

// ---------------------------------------------------------------- K5: sp_logits via bf16 MFMA, direct-from-L2 frags
__global__ __launch_bounds__(256, 3) void k_sp_mfma(
    const unsigned short* __restrict__ hbf, const unsigned short* __restrict__ wbf,
    const float* __restrict__ bias, float* __restrict__ out) {
    const int tid = threadIdx.x;
    const int lane = tid & 63;
    const int wid = tid >> 6;
    const int tok_w = blockIdx.y * 128 + (wid & 1) * 64;
    const int v_w = blockIdx.x * 128 + (wid >> 1) * 64;

    const int lrow = lane & 15;
    const int lk = (lane >> 4) * 8;

    const unsigned short* ha = hbf + (size_t)(tok_w + lrow) * HIDn + lk;
    const unsigned short* wa = wbf + (size_t)(v_w + lrow) * HIDn + lk;

    f32x4 acc[4][4];
#pragma unroll
    for (int m = 0; m < 4; ++m)
#pragma unroll
        for (int n = 0; n < 4; ++n) acc[m][n] = (f32x4){0.f, 0.f, 0.f, 0.f};

#pragma unroll
    for (int ks = 0; ks < 4; ++ks) {
        const int kk = ks * 32;
        short8v a[4], b[4];
#pragma unroll
        for (int m = 0; m < 4; ++m)
            a[m] = *(const short8v*)(ha + (size_t)m * 16 * HIDn + kk);
#pragma unroll
        for (int n = 0; n < 4; ++n)
            b[n] = *(const short8v*)(wa + (size_t)n * 16 * HIDn + kk);
#pragma unroll
        for (int m = 0; m < 4; ++m)
#pragma unroll
            for (int n = 0; n < 4; ++n)
                acc[m][n] = __builtin_amdgcn_mfma_f32_16x16x32_bf16(a[m], b[n], acc[m][n], 0, 0, 0);
    }

    const int r0 = (lane >> 4) * 4;
#pragma unroll
    for (int n = 0; n < 4; ++n) {
        const int col = v_w + n * 16 + lrow;
        if (col < VSPn) {
            const float bv = bias[col];
#pragma unroll
            for (int m = 0; m < 4; ++m) {
                const int row = tok_w + m * 16 + r0;
#pragma unroll
                for (int r = 0; r < 4; ++r)
                    out[(size_t)(row + r) * VSPn + col] = acc[m][n][r] + bv;
            }
        }
    }
}

// ---------------------------------------------------------------- K6: canopy head on h[:, -1, :]
__global__ __launch_bounds__(128) void k_canopy(const float* __restrict__ h,
                                                const float* __restrict__ w1,
                                                const float* __restrict__ b1,
                                                const float* __restrict__ w2,
                                                const float* __restrict__ b2,
                                                float* __restrict__ can) {
    int b = blockIdx.x, o = threadIdx.x;
    __shared__ float r[128];
    const float4* hr = (const float4*)(h + (size_t)(b * Tn + Tn - 1) * HIDn);
    const float4* wr = (const float4*)(w1 + (size_t)o * HIDn);
    float a = b1[o];
#pragma unroll
    for (int kk = 0; kk < 32; ++kk) a += dot4(hr[kk], wr[kk]);
    r[o] = fmaxf(a, 0.f) * w2[o];
    __syncthreads();
    for (int s = 64; s > 0; s >>= 1) {
        if (o < s) r[o] += r[o + s];
        __syncthreads();
    }
    if (o == 0) can[b] = r[0] + b2[0];
}

// ---------------------------------------------------------------- K7: loss + perplexity
__global__ __launch_bounds__(256) void k_finalize(const float* __restrict__ partials,
                                                  const int* __restrict__ counts,
                                                  float* __restrict__ out_loss,
                                                  float* __restrict__ out_ppl) {
    const int tid = threadIdx.x;
    __shared__ float red[256];
    float ps = 0.f;
#pragma unroll
    for (int j = 0; j < (BTn / 4) / 256; ++j) ps += partials[tid * ((BTn / 4) / 256) + j];
    red[tid] = ps;
    __syncthreads();
    for (int s = 128; s > 0; s >>= 1) {
        if (tid < s) red[tid] += red[tid + s];
        __syncthreads();
    }
    float total = red[0];
    __syncthreads();
    float e = 0.f;
    for (int i = tid; i < Kn; i += 256) {
        float p = (float)counts[i] * (1.0f / BTn);
        e += p * logf(p + 1e-12f);
    }
    red[tid] = e;
    __syncthreads();
    for (int s = 128; s > 0; s >>= 1) {
        if (tid < s) red[tid] += red[tid + s];
        __syncthreads();
    }
    if (tid == 0) {
        out_loss[0] = 1.25f * total / (float)((size_t)BTn * EMBn);
        out_ppl[0] = expf(-red[0]);
    }
}

// ----------------------------------------------------------------
extern "C" void kernel_launch(void* const* d_in, const int* in_sizes, int n_in,
                              void* d_out, int out_size, void* d_ws, size_t ws_size,
                              hipStream_t stream) {
    const float* cont = (const float*)d_in[0];
    const float* naip = (const float*)d_in[1];
    const int* cat = (const int*)d_in[2];
    const float* emb_sp = (const float*)d_in[3];
    const float* emb_lc = (const float*)d_in[4];
    const float* conv_w = (const float*)d_in[5];
    const float* conv_b = (const float*)d_in[6];
    const float* npw = (const float*)d_in[7];
    const float* npb = (const float*)d_in[8];
    const float* cpw = (const float*)d_in[9];
    const float* cpb = (const float*)d_in[10];
    const float* caw = (const float*)d_in[11];
    const float* cab = (const float*)d_in[12];
    const float* f1w = (const float*)d_in[13];
    const float* f1b = (const float*)d_in[14];
    const float* f2w = (const float*)d_in[15];
    const float* f2b = (const float*)d_in[16];
    const float* cb = (const float*)d_in[17];
    const float* bb1w = (const float*)d_in[18];
    const float* bb1b = (const float*)d_in[19];
    const float* bb2w = (const float*)d_in[20];
    const float* bb2b = (const float*)d_in[21];
    const float* chw = (const float*)d_in[22];
    const float* chb = (const float*)d_in[23];
    const float* spw = (const float*)d_in[24];
    const float* spb = (const float*)d_in[25];
    const float* lcw = (const float*)d_in[26];
    const float* lcb = (const float*)d_in[27];
    const float* c1w = (const float*)d_in[28];
    const float* c1b = (const float*)d_in[29];
    const float* c2w = (const float*)d_in[30];
    const float* c2b = (const float*)d_in[31];

    float* out = (float*)d_out;
    float* ws = (float*)d_ws;
    float* naip2 = ws + WS_NAIP2;
    float* z_e = ws + WS_ZE;
    float* z_q = ws + WS_ZQ;
    float* h = ws + WS_H;
    float* e_sq = ws + WS_ESQ;
    float* parts = ws + WS_PART;
    int* counts = (int*)(ws + WS_CNTK);
    int* cntT = (int*)(ws + WS_CNTT);
    float* qtok = ws + WS_Q;
    int* cand = (int*)(ws + WS_CAND);
    unsigned short* zbf = (unsigned short*)(ws + WS_ZBF);
    unsigned short* cbbf = (unsigned short*)(ws + WS_CBBF);
    unsigned short* hbf = (unsigned short*)(ws + WS_HBF);
    unsigned short* wbf = (unsigned short*)(ws + WS_WBF);
    float* rcg = ws + WS_RCG;
    float* fused_g = ws + WS_FUSED;
    float* h1g = ws + WS_H1;

    k_esq_zero<<<dim3(Kn / 256), dim3(256), 0, stream>>>(cb, e_sq, counts, cbbf);
    k_rcmax<<<dim3(1), dim3(256), 0, stream>>>(e_sq, rcg);
    k_wcast<<<dim3(VSP_PAD * HIDn / 4 / 256), dim3(256), 0, stream>>>(spw, wbf);
    k_naip<<<dim3(Bn), dim3(128), 0, stream>>>(naip, conv_w, conv_b, npw, npb, naip2);
    k_fused<<<dim3(BTn / 64), dim3(256), 0, stream>>>(cont, cat, emb_sp, emb_lc, cpw, cpb,
                                                      caw, cab, naip2, fused_g);
    k_f1<<<dim3(BTn / 64), dim3(256), 0, stream>>>(fused_g, f1w, f1b, h1g);
    k_f2<<<dim3(BTn / 16), dim3(256), 0, stream>>>(h1g, f2w, f2b, z_e);
    k_zprep<<<dim3(BTn / 4), dim3(256), 0, stream>>>(z_e, zbf, qtok);
    k_vq_sweep<<<dim3(BTn / TOKB), dim3(512), 0, stream>>>(zbf, cbbf, e_sq, qtok, rcg, cntT, cand);
    k_vq_rescore<<<dim3(BTn / 4), dim3(256), 0, stream>>>(cntT, cand, z_e, cb, e_sq, z_q,
                                                          out + O_IDX, counts, parts);
    k_backbone<<<dim3(BTn / 16), dim3(256), 0, stream>>>(z_q, bb1w, bb1b, bb2w, bb2b, chw, chb,
                                                         lcw, lcb, h, hbf, out + O_CONT, out + O_LC);
    k_sp_mfma<<<dim3(VSP_PAD / 128, BTn / 128), dim3(256), 0, stream>>>(hbf, wbf, spb, out + O_SP);
    k_canopy<<<dim3(Bn), dim3(128), 0, stream>>>(h, c1w, c1b, c2w, c2b, out + O_CAN);
    k_finalize<<<dim3(1), dim3(256), 0, stream>>>(parts, counts, out + O_LOSS, out + O_PPL);
}

// Round 15
// 309.025 us; speedup vs baseline: 2.3293x; 1.6297x over previous
//
#include <hip/hip_runtime.h>
#include <cmath>

namespace {
constexpr int Bn = 128, Tn = 128, BTn = Bn * Tn;
constexpr int CONTn = 16, HIDn = 128, EMBn = 64;
constexpr int Kn = 8192, CEn = 6, VSPn = 2000, VLCn = 32, FINn = 3 * HIDn;
constexpr int VSP_PAD = 2048;             // padded vocab for MFMA tiles
constexpr int CAP = 128;                  // max stored VQ candidates per token
constexpr float EPSC = 0.02f;             // rigorous bf16 interval coeff (2^-6 * 1.28)
constexpr int TOKB = 32;                  // tokens per sweep block
constexpr int KCW = 64;                   // codes per wave-chunk
constexpr int NIT = Kn / (KCW * 8);       // 16 chunk-iterations per wave (8 waves)

// ---- workspace layout (float units) ----
constexpr size_t WS_NAIP2 = 0;                               // B*HID
constexpr size_t WS_ZE    = WS_NAIP2 + (size_t)Bn * HIDn;    // BT*EMB
constexpr size_t WS_ZQ    = WS_ZE + (size_t)BTn * EMBn;      // BT*EMB
constexpr size_t WS_H     = WS_ZQ + (size_t)BTn * EMBn;      // BT*HID
constexpr size_t WS_ESQ   = WS_H + (size_t)BTn * HIDn;       // K
constexpr size_t WS_PART  = WS_ESQ + Kn;                     // BT/4 partial loss sums
constexpr size_t WS_CNTK  = WS_PART + BTn / 4;               // K ints (code counts)
constexpr size_t WS_CNTT  = WS_CNTK + Kn;                    // BT ints (candidate counts)
constexpr size_t WS_Q     = WS_CNTT + BTn;                   // BT floats (eps per token)
constexpr size_t WS_CAND  = WS_Q + BTn;                      // BT*CAP ints
constexpr size_t WS_ZBF   = WS_CAND + (size_t)BTn * CAP;     // BT*EMB ushort
constexpr size_t WS_CBBF  = WS_ZBF + (size_t)BTn * EMBn / 2; // K*EMB ushort
constexpr size_t WS_HBF   = WS_CBBF + (size_t)Kn * EMBn / 2; // BT*HID ushort
constexpr size_t WS_WBF   = WS_HBF + (size_t)BTn * HIDn / 2; // VSP_PAD*HID ushort
constexpr size_t WS_RCG   = WS_WBF + (size_t)VSP_PAD * HIDn / 2; // 1 float (global rcmax)

// ---- output layout (float units) ----
constexpr size_t O_CONT = 0;
constexpr size_t O_SP   = O_CONT + (size_t)BTn * CONTn;
constexpr size_t O_LC   = O_SP + (size_t)BTn * VSPn;
constexpr size_t O_CAN  = O_LC + (size_t)BTn * VLCn;
constexpr size_t O_IDX  = O_CAN + Bn;
constexpr size_t O_LOSS = O_IDX + BTn;
constexpr size_t O_PPL  = O_LOSS + 1;
} // namespace

typedef __attribute__((ext_vector_type(8))) short short8v;  // 8 bf16 = 4 VGPR
typedef __attribute__((ext_vector_type(4))) float f32x4;

__device__ __forceinline__ float nan0(float v) {
    return __builtin_isfinite(v) ? v : 0.0f;
}
__device__ __forceinline__ float dot4(float4 a, float4 b) {
    return a.x * b.x + a.y * b.y + a.z * b.z + a.w * b.w;
}
__device__ __forceinline__ unsigned short f2bf(float f) { // RNE, finite-only
    union { float f; unsigned u; } v{f};
    unsigned r = v.u + 0x7FFFu + ((v.u >> 16) & 1u);
    return (unsigned short)(r >> 16);
}
// monotone float<->uint encoding (for atomicMax on floats of any sign)
__device__ __forceinline__ unsigned fenc(float f) {
    unsigned b = __float_as_uint(f);
    return (b & 0x80000000u) ? ~b : (b | 0x80000000u);
}
__device__ __forceinline__ float fdec(unsigned k) {
    unsigned b = (k >> 31) ? (k & 0x7fffffffu) : ~k;
    return __uint_as_float(b);
}

// ---------------------------------------------------------------- K0: zero code counts + e_sq + bf16 codebook
__global__ __launch_bounds__(256) void k_esq_zero(const float* __restrict__ cb,
                                                  float* __restrict__ e_sq,
                                                  int* __restrict__ counts,
                                                  unsigned short* __restrict__ cbbf) {
    int i = blockIdx.x * 256 + threadIdx.x;
    if (i < Kn) {
        counts[i] = 0;
        const float4* r = (const float4*)(cb + (size_t)i * EMBn);
        float s = 0.f;
#pragma unroll
        for (int j = 0; j < 16; ++j) {
            float4 v = r[j];
            s += dot4(v, v);
            unsigned short u[4] = {f2bf(v.x), f2bf(v.y), f2bf(v.z), f2bf(v.w)};
            *(uint2*)(cbbf + (size_t)i * EMBn + j * 4) = *(const uint2*)u;
        }
        e_sq[i] = s;
    }
}

// ---------------------------------------------------------------- K0c: global max codebook norm
__global__ __launch_bounds__(256) void k_rcmax(const float* __restrict__ e_sq,
                                               float* __restrict__ rcg) {
    const int tid = threadIdx.x;
    float m = 0.f;
#pragma unroll
    for (int j = 0; j < Kn / 256; ++j) m = fmaxf(m, e_sq[j * 256 + tid]);
#pragma unroll
    for (int off = 32; off > 0; off >>= 1) m = fmaxf(m, __shfl_xor(m, off));
    __shared__ float wm[4];
    if ((tid & 63) == 0) wm[tid >> 6] = m;
    __syncthreads();
    if (tid == 0)
        rcg[0] = sqrtf(fmaxf(fmaxf(wm[0], wm[1]), fmaxf(wm[2], wm[3]))) * 1.000001f;
}

// ---------------------------------------------------------------- K0b: sp_head_w -> bf16, padded to 2048 rows
__global__ __launch_bounds__(256) void k_wcast(const float* __restrict__ w,
                                               unsigned short* __restrict__ wbf) {
    int i = blockIdx.x * 256 + threadIdx.x;      // float4 index; 32 per row
    int v = i >> 5;
    unsigned short u[4] = {0, 0, 0, 0};
    if (v < VSPn) {
        float4 x = ((const float4*)w)[i];
        u[0] = f2bf(x.x); u[1] = f2bf(x.y); u[2] = f2bf(x.z); u[3] = f2bf(x.w);
    }
    *(uint2*)(wbf + (size_t)i * 4) = *(const uint2*)u;
}

// ---------------------------------------------------------------- K1: naip conv + proj -> naip2 (B x HID)
__global__ __launch_bounds__(128) void k_naip(const float* __restrict__ naip,
                                              const float* __restrict__ conv_w,
                                              const float* __restrict__ conv_b,
                                              const float* __restrict__ pw,
                                              const float* __restrict__ pb,
                                              float* __restrict__ naip2) {
    int b = blockIdx.x, o = threadIdx.x;
    __shared__ float feat[HIDn];
    float acc = conv_b[o];
#pragma unroll
    for (int i = 0; i < 9; ++i) acc += nan0(naip[b * 9 + i]) * conv_w[o * 9 + i];
    feat[o] = fmaxf(acc, 0.f);
    __syncthreads();
    float a2 = pb[o];
    const float4* wr = (const float4*)(pw + (size_t)o * HIDn);
    const float4* fr = (const float4*)feat;
#pragma unroll
    for (int j = 0; j < 32; ++j) a2 += dot4(fr[j], wr[j]);
    naip2[(size_t)b * HIDn + o] = a2;
}

// ---------------------------------------------------------------- K2: fused inputs -> z_e (BT x EMB)
// (round-12 monolithic version — 83 µs, spill-free: 8-reg accumulators only)
__global__ __launch_bounds__(256) void k_ze(
    const float* __restrict__ cont, const int* __restrict__ cat,
    const float* __restrict__ emb_sp, const float* __restrict__ emb_lc,
    const float* __restrict__ cpw, const float* __restrict__ cpb,
    const float* __restrict__ caw, const float* __restrict__ cab,
    const float* __restrict__ f1w, const float* __restrict__ f1b,
    const float* __restrict__ f2w, const float* __restrict__ f2b,
    const float* __restrict__ naip2, float* __restrict__ z_e) {
    const int tok0 = blockIdx.x * 16;
    const int tid = threadIdx.x;
    __shared__ float fused[16][FINn + 4];
    __shared__ float h1[16][HIDn + 4];

    for (int idx = tid; idx < 16 * HIDn; idx += 256) {
        int t = idx >> 7, j = idx & 127;
        int b = (tok0 + t) / Tn;
        fused[t][j] = naip2[(size_t)b * HIDn + j];
    }
    for (int idx = tid; idx < 16 * HIDn; idx += 256) {
        int t = idx >> 7, o = idx & 127;
        int tok = tok0 + t;
        const float4* cp = (const float4*)(cont + (size_t)tok * CONTn);
        const float4* wr = (const float4*)(cpw + (size_t)o * CONTn);
        float a = cpb[o];
#pragma unroll
        for (int q = 0; q < 4; ++q) {
            float4 c4 = cp[q], w4 = wr[q];
            a += nan0(c4.x) * w4.x + nan0(c4.y) * w4.y + nan0(c4.z) * w4.z + nan0(c4.w) * w4.w;
        }
        fused[t][HIDn + o] = a;
    }
    for (int idx = tid; idx < 16 * HIDn; idx += 256) {
        int t = idx >> 7, o = idx & 127;
        int tok = tok0 + t;
        int c0 = cat[tok * 2], c1 = cat[tok * 2 + 1];
        const float* e0 = emb_sp + (size_t)c0 * CEn;
        const float* e1 = emb_lc + (size_t)c1 * CEn;
        const float* wr = caw + (size_t)o * (2 * CEn);
        float a = cab[o];
#pragma unroll
        for (int i = 0; i < CEn; ++i) a += e0[i] * wr[i];
#pragma unroll
        for (int i = 0; i < CEn; ++i) a += e1[i] * wr[CEn + i];
        fused[t][2 * HIDn + o] = a;
    }
    __syncthreads();
    {
        int o = tid >> 1, half = tid & 1;
        float acc[8];
        float bv = f1b[o];
#pragma unroll
        for (int t = 0; t < 8; ++t) acc[t] = bv;
        const float4* wr = (const float4*)(f1w + (size_t)o * FINn);
        for (int kk = 0; kk < FINn / 4; ++kk) {
            float4 w = wr[kk];
#pragma unroll
            for (int t = 0; t < 8; ++t) {
                float4 f = ((const float4*)&fused[half * 8 + t][0])[kk];
                acc[t] += dot4(f, w);
            }
        }
#pragma unroll
        for (int t = 0; t < 8; ++t) h1[half * 8 + t][o] = fmaxf(acc[t], 0.f);
    }
    __syncthreads();
    {
        int o = tid & 63, tg = tid >> 6;
        float acc[4];
        float bv = f2b[o];
#pragma unroll
        for (int t = 0; t < 4; ++t) acc[t] = bv;
        const float4* wr = (const float4*)(f2w + (size_t)o * HIDn);
        for (int kk = 0; kk < HIDn / 4; ++kk) {
            float4 w = wr[kk];
#pragma unroll
            for (int t = 0; t < 4; ++t) {
                float4 f = ((const float4*)&h1[tg * 4 + t][0])[kk];
                acc[t] += dot4(f, w);
            }
        }
#pragma unroll
        for (int t = 0; t < 4; ++t) z_e[(size_t)(tok0 + tg * 4 + t) * EMBn + o] = acc[t];
    }
}

// ---------------------------------------------------------------- K3p: z -> bf16, per-token eps
__global__ __launch_bounds__(256) void k_zprep(const float* __restrict__ z_e,
                                               unsigned short* __restrict__ zbf,
                                               float* __restrict__ qtok) {
    const int lane = threadIdx.x & 63;
    const int tg = threadIdx.x >> 6;
    const int t = blockIdx.x * 4 + tg;
    float zv = z_e[(size_t)t * EMBn + lane];
    zbf[(size_t)t * EMBn + lane] = f2bf(zv);
    float s = zv * zv;
#pragma unroll
    for (int off = 32; off > 0; off >>= 1) s += __shfl_xor(s, off);
    if (lane == 0) qtok[t] = EPSC * sqrtf(s);
}

// ---------------------------------------------------------------- K3a: VQ sweep, barrier-free wave pipelines
__global__ __launch_bounds__(512, 4) void k_vq_sweep(
    const unsigned short* __restrict__ zbf, const unsigned short* __restrict__ cbbf,
    const float* __restrict__ e_sq, const float* __restrict__ qtok,
    const float* __restrict__ rcg,
    int* __restrict__ cntT, int* __restrict__ cand) {
    const int tid = threadIdx.x;
    const int lane = tid & 63;
    const int wid = tid >> 6;          // 0..7
    const int lrow = lane & 15;
    const int g = lane >> 4;           // 0..3
    const int tok0 = blockIdx.x * TOKB;

    __shared__ unsigned tauL[TOKB];    // running max-acc per token (encoded)
    __shared__ int cntL[TOKB];
    if (tid < TOKB) { tauL[tid] = 0u; cntL[tid] = 0; }

    short8v bz[2][2];
#pragma unroll
    for (int n = 0; n < 2; ++n)
#pragma unroll
        for (int kc = 0; kc < 2; ++kc)
            bz[n][kc] = *(const short8v*)(zbf + (size_t)(tok0 + n * 16 + lrow) * EMBn + kc * 32 + g * 8);
    float qn[2];
#pragma unroll
    for (int n = 0; n < 2; ++n) qn[n] = qtok[tok0 + n * 16 + lrow];
    const float rcm = rcg[0];
    __syncthreads(); // tauL/cntL init visible; ONLY barrier before the end

    for (int it = 0; it < NIT; ++it) {
        const int c0 = (it * 8 + wid) * KCW;   // this wave's 64 codes
        short8v ac[4][2];
        float4 e4[4];
#pragma unroll
        for (int m = 0; m < 4; ++m) {
#pragma unroll
            for (int kc = 0; kc < 2; ++kc)
                ac[m][kc] = *(const short8v*)(cbbf + (size_t)(c0 + m * 16 + lrow) * EMBn + kc * 32 + g * 8);
            e4[m] = *(const float4*)(e_sq + c0 + m * 16 + g * 4);
        }
        f32x4 acc[4][2];
#pragma unroll
        for (int m = 0; m < 4; ++m) {
            f32x4 em = {-0.5f * e4[m].x, -0.5f * e4[m].y, -0.5f * e4[m].z, -0.5f * e4[m].w};
            acc[m][0] = em;
            acc[m][1] = em;
        }
#pragma unroll
        for (int kc = 0; kc < 2; ++kc)
#pragma unroll
            for (int m = 0; m < 4; ++m)
#pragma unroll
                for (int n = 0; n < 2; ++n)
                    acc[m][n] = __builtin_amdgcn_mfma_f32_16x16x32_bf16(ac[m][kc], bz[n][kc], acc[m][n], 0, 0, 0);

#pragma unroll
        for (int n = 0; n < 2; ++n) {
            float v = acc[0][n][0];
#pragma unroll
            for (int m = 0; m < 4; ++m)
#pragma unroll
                for (int r = 0; r < 4; ++r) v = fmaxf(v, acc[m][n][r]);
            v = fmaxf(v, __shfl_xor(v, 16));
            v = fmaxf(v, __shfl_xor(v, 32));
            if (lane < 16) atomicMax(&tauL[n * 16 + lane], fenc(v));
            float tf = fmaxf(fdec(tauL[n * 16 + lrow]), v);
            float nthr = tf - qn[n] * rcm;
            const int tn = n * 16 + lrow;
#pragma unroll
            for (int m = 0; m < 4; ++m)
#pragma unroll
                for (int r = 0; r < 4; ++r)
                    if (acc[m][n][r] >= nthr) {
                        int slot = atomicAdd(&cntL[tn], 1);
                        if (slot < CAP)
                            cand[(size_t)(tok0 + tn) * CAP + slot] = c0 + m * 16 + g * 4 + r;
                    }
        }
    }
    __syncthreads();
    if (tid < TOKB) cntT[tok0 + tid] = cntL[tid];
}

// ---------------------------------------------------------------- K3b: exact f32 rescore of candidates (+ fallback)
__global__ __launch_bounds__(256) void k_vq_rescore(
    const int* __restrict__ cntT, const int* __restrict__ cand,
    const float* __restrict__ z_e, const float* __restrict__ cb,
    const float* __restrict__ e_sq,
    float* __restrict__ z_q, float* __restrict__ idx_out,
    int* __restrict__ counts, float* __restrict__ partials) {
    const int lane = threadIdx.x & 63;
    const int tg = threadIdx.x >> 6;
    const int t = blockIdx.x * 4 + tg;
    __shared__ float psum[4];

    float4 z[16];
    const float4* zr = (const float4*)(z_e + (size_t)t * EMBn);
#pragma unroll
    for (int q = 0; q < 16; ++q) z[q] = zr[q];

    const int n = cntT[t];
    float best = INFINITY;
    int bi = Kn;

    if (n > 0 && n <= CAP) {
        for (int s = lane; s < n; s += 64) {
            int c = cand[(size_t)t * CAP + s];
            const float4* cp = (const float4*)(cb + (size_t)c * EMBn);
            float a = 0.f;
#pragma unroll
            for (int q = 0; q < 16; ++q) a += dot4(z[q], cp[q]);
            float d = e_sq[c] - 2.f * a;
            if (d < best || (d == best && c < bi)) { best = d; bi = c; }
        }
    } else { // overflow (pathological) or empty: exact full scan
        for (int c0 = 0; c0 < Kn; c0 += 64) {
            int c = c0 + lane;
            const float4* cp = (const float4*)(cb + (size_t)c * EMBn);
            float a = 0.f;
#pragma unroll
            for (int q = 0; q < 16; ++q) a += dot4(z[q], cp[q]);
            float d = e_sq[c] - 2.f * a;
            if (d < best) { best = d; bi = c; } // ascending c per lane
        }
    }
#pragma unroll
    for (int off = 32; off > 0; off >>= 1) {
        float od = __shfl_xor(best, off);
        int oi = __shfl_xor(bi, off);
        if (od < best || (od == best && oi < bi)) { best = od; bi = oi; }
    }

    float cv = cb[(size_t)bi * EMBn + lane];
    z_q[(size_t)t * EMBn + lane] = cv;
    float zv = z_e[(size_t)t * EMBn + lane];
    float diff = zv - cv;
    float s = diff * diff;
#pragma unroll
    for (int off = 32; off > 0; off >>= 1) s += __shfl_xor(s, off);
    if (lane == 0) {
        psum[tg] = s;
        idx_out[t] = (float)bi;
        atomicAdd(&counts[bi], 1);
    }
    __syncthreads();
    if (threadIdx.x == 0) partials[blockIdx.x] = psum[0] + psum[1] + psum[2] + psum[3];
}

// ---------------------------------------------------------------- K4: backbone + small heads (+ h in bf16)
__global__ __launch_bounds__(256) void k_backbone(
    const float* __restrict__ z_q,
    const float* __restrict__ bb1w, const float* __restrict__ bb1b,
    const float* __restrict__ bb2w, const float* __restrict__ bb2b,
    const float* __restrict__ chw, const float* __restrict__ chb,
    const float* __restrict__ lcw, const float* __restrict__ lcb,
    float* __restrict__ h_out, unsigned short* __restrict__ hbf_out,
    float* __restrict__ cont_rec, float* __restrict__ lc_out) {
    const int tid = threadIdx.x;
    const int tok0 = blockIdx.x * 16;
    __shared__ float zq[16][68];
    __shared__ float h1[16][HIDn + 4];
    __shared__ float h2[16][HIDn + 4];
    {
        int t = tid >> 4, q = tid & 15;
        ((float4*)&zq[t][0])[q] = ((const float4*)(z_q + (size_t)(tok0 + t) * EMBn))[q];
    }
    __syncthreads();
    {
        int o = tid >> 1, half = tid & 1;
        float acc[8];
        float bv = bb1b[o];
#pragma unroll
        for (int t = 0; t < 8; ++t) acc[t] = bv;
        const float4* wr = (const float4*)(bb1w + (size_t)o * EMBn);
#pragma unroll
        for (int kk = 0; kk < 16; ++kk) {
            float4 w = wr[kk];
#pragma unroll
            for (int t = 0; t < 8; ++t) acc[t] += dot4(((const float4*)&zq[half * 8 + t][0])[kk], w);
        }
#pragma unroll
        for (int t = 0; t < 8; ++t) h1[half * 8 + t][o] = fmaxf(acc[t], 0.f);
    }
    __syncthreads();
    {
        int o = tid >> 1, half = tid & 1;
        float acc[8];
        float bv = bb2b[o];
#pragma unroll
        for (int t = 0; t < 8; ++t) acc[t] = bv;
        const float4* wr = (const float4*)(bb2w + (size_t)o * HIDn);
        for (int kk = 0; kk < 32; ++kk) {
            float4 w = wr[kk];
#pragma unroll
            for (int t = 0; t < 8; ++t) acc[t] += dot4(((const float4*)&h1[half * 8 + t][0])[kk], w);
        }
#pragma unroll
        for (int t = 0; t < 8; ++t) {
            float v = fmaxf(acc[t], 0.f);
            h2[half * 8 + t][o] = v;
            h_out[(size_t)(tok0 + half * 8 + t) * HIDn + o] = v;
            hbf_out[(size_t)(tok0 + half * 8 + t) * HIDn + o] = f2bf(v);
        }
    }
    __syncthreads();
    {
        int t = tid >> 4, o = tid & 15;
        float a = chb[o];
        const float4* wr = (const float4*)(chw + (size_t)o * HIDn);
#pragma unroll
        for (int kk = 0; kk < 32; ++kk) a += dot4(((const float4*)&h2[t][0])[kk], wr[kk]);
        cont_rec[(size_t)(tok0 + t) * CONTn + o] = a;
    }
    for (int idx = tid; idx < 16 * 32; idx += 256) {
        int t = idx >> 5, o = idx & 31;
        float a = lcb[o];
        const float4* wr = (const float4*)(lcw + (size_t)o * HIDn);
#pragma unroll
        for (int kk = 0; kk < 32; ++kk) a += dot4(((const float4*)&h2[t][0])[kk], wr[kk]);
        lc_out[(size_t)(tok0 + t) * VLCn + o] = a;
    }
}

// ---------------------------------------------------------------- K5: sp_logits via bf16 MFMA, direct-from-L2 frags
__global__ __launch_bounds__(256, 3) void k_sp_mfma(
    const unsigned short* __restrict__ hbf, const unsigned short* __restrict__ wbf,
    const float* __restrict__ bias, float* __restrict__ out) {
    const int tid = threadIdx.x;
    const int lane = tid & 63;
    const int wid = tid >> 6;
    const int tok_w = blockIdx.y * 128 + (wid & 1) * 64;
    const int v_w = blockIdx.x * 128 + (wid >> 1) * 64;

    const int lrow = lane & 15;
    const int lk = (lane >> 4) * 8;

    const unsigned short* ha = hbf + (size_t)(tok_w + lrow) * HIDn + lk;
    const unsigned short* wa = wbf + (size_t)(v_w + lrow) * HIDn + lk;

    f32x4 acc[4][4];
#pragma unroll
    for (int m = 0; m < 4; ++m)
#pragma unroll
        for (int n = 0; n < 4; ++n) acc[m][n] = (f32x4){0.f, 0.f, 0.f, 0.f};

#pragma unroll
    for (int ks = 0; ks < 4; ++ks) {
        const int kk = ks * 32;
        short8v a[4], b[4];
#pragma unroll
        for (int m = 0; m < 4; ++m)
            a[m] = *(const short8v*)(ha + (size_t)m * 16 * HIDn + kk);
#pragma unroll
        for (int n = 0; n < 4; ++n)
            b[n] = *(const short8v*)(wa + (size_t)n * 16 * HIDn + kk);
#pragma unroll
        for (int m = 0; m < 4; ++m)
#pragma unroll
            for (int n = 0; n < 4; ++n)
                acc[m][n] = __builtin_amdgcn_mfma_f32_16x16x32_bf16(a[m], b[n], acc[m][n], 0, 0, 0);
    }

    const int r0 = (lane >> 4) * 4;
#pragma unroll
    for (int n = 0; n < 4; ++n) {
        const int col = v_w + n * 16 + lrow;
        if (col < VSPn) {
            const float bv = bias[col];
#pragma unroll
            for (int m = 0; m < 4; ++m) {
                const int row = tok_w + m * 16 + r0;
#pragma unroll
                for (int r = 0; r < 4; ++r)
                    out[(size_t)(row + r) * VSPn + col] = acc[m][n][r] + bv;
            }
        }
    }
}

// ---------------------------------------------------------------- K6: canopy head on h[:, -1, :]
__global__ __launch_bounds__(128) void k_canopy(const float* __restrict__ h,
                                                const float* __restrict__ w1,
                                                const float* __restrict__ b1,
                                                const float* __restrict__ w2,
                                                const float* __restrict__ b2,
                                                float* __restrict__ can) {
    int b = blockIdx.x, o = threadIdx.x;
    __shared__ float r[128];
    const float4* hr = (const float4*)(h + (size_t)(b * Tn + Tn - 1) * HIDn);
    const float4* wr = (const float4*)(w1 + (size_t)o * HIDn);
    float a = b1[o];
#pragma unroll
    for (int kk = 0; kk < 32; ++kk) a += dot4(hr[kk], wr[kk]);
    r[o] = fmaxf(a, 0.f) * w2[o];
    __syncthreads();
    for (int s = 64; s > 0; s >>= 1) {
        if (o < s) r[o] += r[o + s];
        __syncthreads();
    }
    if (o == 0) can[b] = r[0] + b2[0];
}

// ---------------------------------------------------------------- K7: loss + perplexity
__global__ __launch_bounds__(256) void k_finalize(const float* __restrict__ partials,
                                                  const int* __restrict__ counts,
                                                  float* __restrict__ out_loss,
                                                  float* __restrict__ out_ppl) {
    const int tid = threadIdx.x;
    __shared__ float red[256];
    float ps = 0.f;
#pragma unroll
    for (int j = 0; j < (BTn / 4) / 256; ++j) ps += partials[tid * ((BTn / 4) / 256) + j];
    red[tid] = ps;
    __syncthreads();
    for (int s = 128; s > 0; s >>= 1) {
        if (tid < s) red[tid] += red[tid + s];
        __syncthreads();
    }
    float total = red[0];
    __syncthreads();
    float e = 0.f;
    for (int i = tid; i < Kn; i += 256) {
        float p = (float)counts[i] * (1.0f / BTn);
        e += p * logf(p + 1e-12f);
    }
    red[tid] = e;
    __syncthreads();
    for (int s = 128; s > 0; s >>= 1) {
        if (tid < s) red[tid] += red[tid + s];
        __syncthreads();
    }
    if (tid == 0) {
        out_loss[0] = 1.25f * total / (float)((size_t)BTn * EMBn);
        out_ppl[0] = expf(-red[0]);
    }
}

// ----------------------------------------------------------------
extern "C" void kernel_launch(void* const* d_in, const int* in_sizes, int n_in,
                              void* d_out, int out_size, void* d_ws, size_t ws_size,
                              hipStream_t stream) {
    const float* cont = (const float*)d_in[0];
    const float* naip = (const float*)d_in[1];
    const int* cat = (const int*)d_in[2];
    const float* emb_sp = (const float*)d_in[3];
    const float* emb_lc = (const float*)d_in[4];
    const float* conv_w = (const float*)d_in[5];
    const float* conv_b = (const float*)d_in[6];
    const float* npw = (const float*)d_in[7];
    const float* npb = (const float*)d_in[8];
    const float* cpw = (const float*)d_in[9];
    const float* cpb = (const float*)d_in[10];
    const float* caw = (const float*)d_in[11];
    const float* cab = (const float*)d_in[12];
    const float* f1w = (const float*)d_in[13];
    const float* f1b = (const float*)d_in[14];
    const float* f2w = (const float*)d_in[15];
    const float* f2b = (const float*)d_in[16];
    const float* cb = (const float*)d_in[17];
    const float* bb1w = (const float*)d_in[18];
    const float* bb1b = (const float*)d_in[19];
    const float* bb2w = (const float*)d_in[20];
    const float* bb2b = (const float*)d_in[21];
    const float* chw = (const float*)d_in[22];
    const float* chb = (const float*)d_in[23];
    const float* spw = (const float*)d_in[24];
    const float* spb = (const float*)d_in[25];
    const float* lcw = (const float*)d_in[26];
    const float* lcb = (const float*)d_in[27];
    const float* c1w = (const float*)d_in[28];
    const float* c1b = (const float*)d_in[29];
    const float* c2w = (const float*)d_in[30];
    const float* c2b = (const float*)d_in[31];

    float* out = (float*)d_out;
    float* ws = (float*)d_ws;
    float* naip2 = ws + WS_NAIP2;
    float* z_e = ws + WS_ZE;
    float* z_q = ws + WS_ZQ;
    float* h = ws + WS_H;
    float* e_sq = ws + WS_ESQ;
    float* parts = ws + WS_PART;
    int* counts = (int*)(ws + WS_CNTK);
    int* cntT = (int*)(ws + WS_CNTT);
    float* qtok = ws + WS_Q;
    int* cand = (int*)(ws + WS_CAND);
    unsigned short* zbf = (unsigned short*)(ws + WS_ZBF);
    unsigned short* cbbf = (unsigned short*)(ws + WS_CBBF);
    unsigned short* hbf = (unsigned short*)(ws + WS_HBF);
    unsigned short* wbf = (unsigned short*)(ws + WS_WBF);
    float* rcg = ws + WS_RCG;

    k_esq_zero<<<dim3(Kn / 256), dim3(256), 0, stream>>>(cb, e_sq, counts, cbbf);
    k_rcmax<<<dim3(1), dim3(256), 0, stream>>>(e_sq, rcg);
    k_wcast<<<dim3(VSP_PAD * HIDn / 4 / 256), dim3(256), 0, stream>>>(spw, wbf);
    k_naip<<<dim3(Bn), dim3(128), 0, stream>>>(naip, conv_w, conv_b, npw, npb, naip2);
    k_ze<<<dim3(BTn / 16), dim3(256), 0, stream>>>(cont, cat, emb_sp, emb_lc, cpw, cpb, caw, cab,
                                                   f1w, f1b, f2w, f2b, naip2, z_e);
    k_zprep<<<dim3(BTn / 4), dim3(256), 0, stream>>>(z_e, zbf, qtok);
    k_vq_sweep<<<dim3(BTn / TOKB), dim3(512), 0, stream>>>(zbf, cbbf, e_sq, qtok, rcg, cntT, cand);
    k_vq_rescore<<<dim3(BTn / 4), dim3(256), 0, stream>>>(cntT, cand, z_e, cb, e_sq, z_q,
                                                          out + O_IDX, counts, parts);
    k_backbone<<<dim3(BTn / 16), dim3(256), 0, stream>>>(z_q, bb1w, bb1b, bb2w, bb2b, chw, chb,
                                                         lcw, lcb, h, hbf, out + O_CONT, out + O_LC);
    k_sp_mfma<<<dim3(VSP_PAD / 128, BTn / 128), dim3(256), 0, stream>>>(hbf, wbf, spb, out + O_SP);
    k_canopy<<<dim3(Bn), dim3(128), 0, stream>>>(h, c1w, c1b, c2w, c2b, out + O_CAN);
    k_finalize<<<dim3(1), dim3(256), 0, stream>>>(parts, counts, out + O_LOSS, out + O_PPL);
}

// Round 16
// 308.169 us; speedup vs baseline: 2.3358x; 1.0028x over previous
//
#include <hip/hip_runtime.h>
#include <cmath>

namespace {
constexpr int Bn = 128, Tn = 128, BTn = Bn * Tn;
constexpr int CONTn = 16, HIDn = 128, EMBn = 64;
constexpr int Kn = 8192, CEn = 6, VSPn = 2000, VLCn = 32, FINn = 3 * HIDn;
constexpr int VSP_PAD = 2048;             // padded vocab for MFMA tiles
constexpr int CAP = 128;                  // max stored VQ candidates per token
constexpr float EPSC = 0.02f;             // rigorous bf16 interval coeff (2^-6 * 1.28)
constexpr int TOKB = 32;                  // tokens per sweep block
constexpr int KCW = 64;                   // codes per wave-chunk
constexpr int NIT = Kn / (KCW * 8);       // 16 chunk-iterations per wave (8 waves)

// ---- workspace layout (float units) ----
constexpr size_t WS_NAIP2 = 0;                               // B*HID
constexpr size_t WS_ZE    = WS_NAIP2 + (size_t)Bn * HIDn;    // BT*EMB
constexpr size_t WS_ZQ    = WS_ZE + (size_t)BTn * EMBn;      // BT*EMB
constexpr size_t WS_H     = WS_ZQ + (size_t)BTn * EMBn;      // BT*HID
constexpr size_t WS_ESQ   = WS_H + (size_t)BTn * HIDn;       // K
constexpr size_t WS_PART  = WS_ESQ + Kn;                     // BT/4 partial loss sums
constexpr size_t WS_CNTK  = WS_PART + BTn / 4;               // K ints (code counts)
constexpr size_t WS_CNTT  = WS_CNTK + Kn;                    // BT ints (candidate counts)
constexpr size_t WS_Q     = WS_CNTT + BTn;                   // BT floats (eps per token)
constexpr size_t WS_CAND  = WS_Q + BTn;                      // BT*CAP ints
constexpr size_t WS_ZBF   = WS_CAND + (size_t)BTn * CAP;     // BT*EMB ushort
constexpr size_t WS_CBBF  = WS_ZBF + (size_t)BTn * EMBn / 2; // K*EMB ushort
constexpr size_t WS_HBF   = WS_CBBF + (size_t)Kn * EMBn / 2; // BT*HID ushort
constexpr size_t WS_WBF   = WS_HBF + (size_t)BTn * HIDn / 2; // VSP_PAD*HID ushort
constexpr size_t WS_RCG   = WS_WBF + (size_t)VSP_PAD * HIDn / 2; // 1 float (global rcmax)

// ---- output layout (float units) ----
constexpr size_t O_CONT = 0;
constexpr size_t O_SP   = O_CONT + (size_t)BTn * CONTn;
constexpr size_t O_LC   = O_SP + (size_t)BTn * VSPn;
constexpr size_t O_CAN  = O_LC + (size_t)BTn * VLCn;
constexpr size_t O_IDX  = O_CAN + Bn;
constexpr size_t O_LOSS = O_IDX + BTn;
constexpr size_t O_PPL  = O_LOSS + 1;
} // namespace

typedef __attribute__((ext_vector_type(8))) short short8v;  // 8 bf16 = 4 VGPR
typedef __attribute__((ext_vector_type(4))) float f32x4;

__device__ __forceinline__ float nan0(float v) {
    return __builtin_isfinite(v) ? v : 0.0f;
}
__device__ __forceinline__ float dot4(float4 a, float4 b) {
    return a.x * b.x + a.y * b.y + a.z * b.z + a.w * b.w;
}
__device__ __forceinline__ unsigned short f2bf(float f) { // RNE, finite-only
    union { float f; unsigned u; } v{f};
    unsigned r = v.u + 0x7FFFu + ((v.u >> 16) & 1u);
    return (unsigned short)(r >> 16);
}
// monotone float<->uint encoding (for atomicMax on floats of any sign)
__device__ __forceinline__ unsigned fenc(float f) {
    unsigned b = __float_as_uint(f);
    return (b & 0x80000000u) ? ~b : (b | 0x80000000u);
}
__device__ __forceinline__ float fdec(unsigned k) {
    unsigned b = (k >> 31) ? (k & 0x7fffffffu) : ~k;
    return __uint_as_float(b);
}

// ---------------------------------------------------------------- K0: zero code counts + e_sq + bf16 codebook
__global__ __launch_bounds__(256) void k_esq_zero(const float* __restrict__ cb,
                                                  float* __restrict__ e_sq,
                                                  int* __restrict__ counts,
                                                  unsigned short* __restrict__ cbbf) {
    int i = blockIdx.x * 256 + threadIdx.x;
    if (i < Kn) {
        counts[i] = 0;
        const float4* r = (const float4*)(cb + (size_t)i * EMBn);
        float s = 0.f;
#pragma unroll
        for (int j = 0; j < 16; ++j) {
            float4 v = r[j];
            s += dot4(v, v);
            unsigned short u[4] = {f2bf(v.x), f2bf(v.y), f2bf(v.z), f2bf(v.w)};
            *(uint2*)(cbbf + (size_t)i * EMBn + j * 4) = *(const uint2*)u;
        }
        e_sq[i] = s;
    }
}

// ---------------------------------------------------------------- K0c: global max codebook norm
__global__ __launch_bounds__(256) void k_rcmax(const float* __restrict__ e_sq,
                                               float* __restrict__ rcg) {
    const int tid = threadIdx.x;
    float m = 0.f;
#pragma unroll
    for (int j = 0; j < Kn / 256; ++j) m = fmaxf(m, e_sq[j * 256 + tid]);
#pragma unroll
    for (int off = 32; off > 0; off >>= 1) m = fmaxf(m, __shfl_xor(m, off));
    __shared__ float wm[4];
    if ((tid & 63) == 0) wm[tid >> 6] = m;
    __syncthreads();
    if (tid == 0)
        rcg[0] = sqrtf(fmaxf(fmaxf(wm[0], wm[1]), fmaxf(wm[2], wm[3]))) * 1.000001f;
}

// ---------------------------------------------------------------- K0b: sp_head_w -> bf16, padded to 2048 rows
__global__ __launch_bounds__(256) void k_wcast(const float* __restrict__ w,
                                               unsigned short* __restrict__ wbf) {
    int i = blockIdx.x * 256 + threadIdx.x;      // float4 index; 32 per row
    int v = i >> 5;
    unsigned short u[4] = {0, 0, 0, 0};
    if (v < VSPn) {
        float4 x = ((const float4*)w)[i];
        u[0] = f2bf(x.x); u[1] = f2bf(x.y); u[2] = f2bf(x.z); u[3] = f2bf(x.w);
    }
    *(uint2*)(wbf + (size_t)i * 4) = *(const uint2*)u;
}

// ---------------------------------------------------------------- K1: naip conv + proj -> naip2 (B x HID)
__global__ __launch_bounds__(128) void k_naip(const float* __restrict__ naip,
                                              const float* __restrict__ conv_w,
                                              const float* __restrict__ conv_b,
                                              const float* __restrict__ pw,
                                              const float* __restrict__ pb,
                                              float* __restrict__ naip2) {
    int b = blockIdx.x, o = threadIdx.x;
    __shared__ float feat[HIDn];
    float acc = conv_b[o];
#pragma unroll
    for (int i = 0; i < 9; ++i) acc += nan0(naip[b * 9 + i]) * conv_w[o * 9 + i];
    feat[o] = fmaxf(acc, 0.f);
    __syncthreads();
    float a2 = pb[o];
    const float4* wr = (const float4*)(pw + (size_t)o * HIDn);
    const float4* fr = (const float4*)feat;
#pragma unroll
    for (int j = 0; j < 32; ++j) a2 += dot4(fr[j], wr[j]);
    naip2[(size_t)b * HIDn + o] = a2;
}

// ---------------------------------------------------------------- K2: fused inputs -> z_e (BT x EMB)
// 32-token blocks (grid 512 = 2 blocks/CU exactly). Phase B: acc[16] per thread
// (one output x 16 tokens, (256,2) regime proven spill-free in r3), unroll-2 kk
// loop batches two independent f1w loads. Per-(token,output) accumulation chain
// (bias init + ascending kk + left-assoc dot4) unchanged => h1/z_e bit-identical.
// LDS exactly 64 KB: fused[32][384] + h1[32][128] (hot reads are wave-broadcast).
__global__ __launch_bounds__(256, 2) void k_ze(
    const float* __restrict__ cont, const int* __restrict__ cat,
    const float* __restrict__ emb_sp, const float* __restrict__ emb_lc,
    const float* __restrict__ cpw, const float* __restrict__ cpb,
    const float* __restrict__ caw, const float* __restrict__ cab,
    const float* __restrict__ f1w, const float* __restrict__ f1b,
    const float* __restrict__ f2w, const float* __restrict__ f2b,
    const float* __restrict__ naip2, float* __restrict__ z_e) {
    const int tok0 = blockIdx.x * 32;
    const int tid = threadIdx.x;
    __shared__ float fused[32][FINn];     // stride 384 floats (16B-aligned rows)
    __shared__ float h1[32][HIDn];        // stride 128

    for (int idx = tid; idx < 32 * HIDn; idx += 256) {
        int t = idx >> 7, j = idx & 127;
        int b = (tok0 + t) / Tn;
        fused[t][j] = naip2[(size_t)b * HIDn + j];
    }
    for (int idx = tid; idx < 32 * HIDn; idx += 256) {
        int t = idx >> 7, o = idx & 127;
        int tok = tok0 + t;
        const float4* cp = (const float4*)(cont + (size_t)tok * CONTn);
        const float4* wr = (const float4*)(cpw + (size_t)o * CONTn);
        float a = cpb[o];
#pragma unroll
        for (int q = 0; q < 4; ++q) {
            float4 c4 = cp[q], w4 = wr[q];
            a += nan0(c4.x) * w4.x + nan0(c4.y) * w4.y + nan0(c4.z) * w4.z + nan0(c4.w) * w4.w;
        }
        fused[t][HIDn + o] = a;
    }
    for (int idx = tid; idx < 32 * HIDn; idx += 256) {
        int t = idx >> 7, o = idx & 127;
        int tok = tok0 + t;
        int c0 = cat[tok * 2], c1 = cat[tok * 2 + 1];
        const float* e0 = emb_sp + (size_t)c0 * CEn;
        const float* e1 = emb_lc + (size_t)c1 * CEn;
        const float* wr = caw + (size_t)o * (2 * CEn);
        float a = cab[o];
#pragma unroll
        for (int i = 0; i < CEn; ++i) a += e0[i] * wr[i];
#pragma unroll
        for (int i = 0; i < CEn; ++i) a += e1[i] * wr[CEn + i];
        fused[t][2 * HIDn + o] = a;
    }
    __syncthreads();
    // B: h1 = relu(fused @ f1w^T + b); one output x 16 tokens per thread
    {
        int o = tid >> 1, half = tid & 1;
        float acc[16];
        float bv = f1b[o];
#pragma unroll
        for (int t = 0; t < 16; ++t) acc[t] = bv;
        const float4* wr = (const float4*)(f1w + (size_t)o * FINn);
#pragma unroll 2
        for (int kk = 0; kk < FINn / 4; ++kk) {
            float4 w = wr[kk];
#pragma unroll
            for (int t = 0; t < 16; ++t) {
                float4 f = ((const float4*)&fused[half * 16 + t][0])[kk];
                acc[t] += dot4(f, w);
            }
        }
#pragma unroll
        for (int t = 0; t < 16; ++t) h1[half * 16 + t][o] = fmaxf(acc[t], 0.f);
    }
    __syncthreads();
    // C: z_e = h1 @ f2w^T + b; one output x 8 tokens per thread
    {
        int o = tid & 63, tg = tid >> 6;
        float acc[8];
        float bv = f2b[o];
#pragma unroll
        for (int t = 0; t < 8; ++t) acc[t] = bv;
        const float4* wr = (const float4*)(f2w + (size_t)o * HIDn);
        for (int kk = 0; kk < HIDn / 4; ++kk) {
            float4 w = wr[kk];
#pragma unroll
            for (int t = 0; t < 8; ++t) {
                float4 f = ((const float4*)&h1[tg * 8 + t][0])[kk];
                acc[t] += dot4(f, w);
            }
        }
#pragma unroll
        for (int t = 0; t < 8; ++t) z_e[(size_t)(tok0 + tg * 8 + t) * EMBn + o] = acc[t];
    }
}

// ---------------------------------------------------------------- K3p: z -> bf16, per-token eps
__global__ __launch_bounds__(256) void k_zprep(const float* __restrict__ z_e,
                                               unsigned short* __restrict__ zbf,
                                               float* __restrict__ qtok) {
    const int lane = threadIdx.x & 63;
    const int tg = threadIdx.x >> 6;
    const int t = blockIdx.x * 4 + tg;
    float zv = z_e[(size_t)t * EMBn + lane];
    zbf[(size_t)t * EMBn + lane] = f2bf(zv);
    float s = zv * zv;
#pragma unroll
    for (int off = 32; off > 0; off >>= 1) s += __shfl_xor(s, off);
    if (lane == 0) qtok[t] = EPSC * sqrtf(s);
}

// ---------------------------------------------------------------- K3a: VQ sweep, barrier-free wave pipelines
__global__ __launch_bounds__(512, 4) void k_vq_sweep(
    const unsigned short* __restrict__ zbf, const unsigned short* __restrict__ cbbf,
    const float* __restrict__ e_sq, const float* __restrict__ qtok,
    const float* __restrict__ rcg,
    int* __restrict__ cntT, int* __restrict__ cand) {
    const int tid = threadIdx.x;
    const int lane = tid & 63;
    const int wid = tid >> 6;          // 0..7
    const int lrow = lane & 15;
    const int g = lane >> 4;           // 0..3
    const int tok0 = blockIdx.x * TOKB;

    __shared__ unsigned tauL[TOKB];    // running max-acc per token (encoded)
    __shared__ int cntL[TOKB];
    if (tid < TOKB) { tauL[tid] = 0u; cntL[tid] = 0; }

    short8v bz[2][2];
#pragma unroll
    for (int n = 0; n < 2; ++n)
#pragma unroll
        for (int kc = 0; kc < 2; ++kc)
            bz[n][kc] = *(const short8v*)(zbf + (size_t)(tok0 + n * 16 + lrow) * EMBn + kc * 32 + g * 8);
    float qn[2];
#pragma unroll
    for (int n = 0; n < 2; ++n) qn[n] = qtok[tok0 + n * 16 + lrow];
    const float rcm = rcg[0];
    __syncthreads(); // tauL/cntL init visible; ONLY barrier before the end

    for (int it = 0; it < NIT; ++it) {
        const int c0 = (it * 8 + wid) * KCW;   // this wave's 64 codes
        short8v ac[4][2];
        float4 e4[4];
#pragma unroll
        for (int m = 0; m < 4; ++m) {
#pragma unroll
            for (int kc = 0; kc < 2; ++kc)
                ac[m][kc] = *(const short8v*)(cbbf + (size_t)(c0 + m * 16 + lrow) * EMBn + kc * 32 + g * 8);
            e4[m] = *(const float4*)(e_sq + c0 + m * 16 + g * 4);
        }
        f32x4 acc[4][2];
#pragma unroll
        for (int m = 0; m < 4; ++m) {
            f32x4 em = {-0.5f * e4[m].x, -0.5f * e4[m].y, -0.5f * e4[m].z, -0.5f * e4[m].w};
            acc[m][0] = em;
            acc[m][1] = em;
        }
#pragma unroll
        for (int kc = 0; kc < 2; ++kc)
#pragma unroll
            for (int m = 0; m < 4; ++m)
#pragma unroll
                for (int n = 0; n < 2; ++n)
                    acc[m][n] = __builtin_amdgcn_mfma_f32_16x16x32_bf16(ac[m][kc], bz[n][kc], acc[m][n], 0, 0, 0);

#pragma unroll
        for (int n = 0; n < 2; ++n) {
            float v = acc[0][n][0];
#pragma unroll
            for (int m = 0; m < 4; ++m)
#pragma unroll
                for (int r = 0; r < 4; ++r) v = fmaxf(v, acc[m][n][r]);
            v = fmaxf(v, __shfl_xor(v, 16));
            v = fmaxf(v, __shfl_xor(v, 32));
            if (lane < 16) atomicMax(&tauL[n * 16 + lane], fenc(v));
            float tf = fmaxf(fdec(tauL[n * 16 + lrow]), v);
            float nthr = tf - qn[n] * rcm;
            const int tn = n * 16 + lrow;
#pragma unroll
            for (int m = 0; m < 4; ++m)
#pragma unroll
                for (int r = 0; r < 4; ++r)
                    if (acc[m][n][r] >= nthr) {
                        int slot = atomicAdd(&cntL[tn], 1);
                        if (slot < CAP)
                            cand[(size_t)(tok0 + tn) * CAP + slot] = c0 + m * 16 + g * 4 + r;
                    }
        }
    }
    __syncthreads();
    if (tid < TOKB) cntT[tok0 + tid] = cntL[tid];
}

// ---------------------------------------------------------------- K3b: exact f32 rescore of candidates (+ fallback)
__global__ __launch_bounds__(256) void k_vq_rescore(
    const int* __restrict__ cntT, const int* __restrict__ cand,
    const float* __restrict__ z_e, const float* __restrict__ cb,
    const float* __restrict__ e_sq,
    float* __restrict__ z_q, float* __restrict__ idx_out,
    int* __restrict__ counts, float* __restrict__ partials) {
    const int lane = threadIdx.x & 63;
    const int tg = threadIdx.x >> 6;
    const int t = blockIdx.x * 4 + tg;
    __shared__ float psum[4];

    float4 z[16];
    const float4* zr = (const float4*)(z_e + (size_t)t * EMBn);
#pragma unroll
    for (int q = 0; q < 16; ++q) z[q] = zr[q];

    const int n = cntT[t];
    float best = INFINITY;
    int bi = Kn;

    if (n > 0 && n <= CAP) {
        for (int s = lane; s < n; s += 64) {
            int c = cand[(size_t)t * CAP + s];
            const float4* cp = (const float4*)(cb + (size_t)c * EMBn);
            float a = 0.f;
#pragma unroll
            for (int q = 0; q < 16; ++q) a += dot4(z[q], cp[q]);
            float d = e_sq[c] - 2.f * a;
            if (d < best || (d == best && c < bi)) { best = d; bi = c; }
        }
    } else { // overflow (pathological) or empty: exact full scan
        for (int c0 = 0; c0 < Kn; c0 += 64) {
            int c = c0 + lane;
            const float4* cp = (const float4*)(cb + (size_t)c * EMBn);
            float a = 0.f;
#pragma unroll
            for (int q = 0; q < 16; ++q) a += dot4(z[q], cp[q]);
            float d = e_sq[c] - 2.f * a;
            if (d < best) { best = d; bi = c; } // ascending c per lane
        }
    }
#pragma unroll
    for (int off = 32; off > 0; off >>= 1) {
        float od = __shfl_xor(best, off);
        int oi = __shfl_xor(bi, off);
        if (od < best || (od == best && oi < bi)) { best = od; bi = oi; }
    }

    float cv = cb[(size_t)bi * EMBn + lane];
    z_q[(size_t)t * EMBn + lane] = cv;
    float zv = z_e[(size_t)t * EMBn + lane];
    float diff = zv - cv;
    float s = diff * diff;
#pragma unroll
    for (int off = 32; off > 0; off >>= 1) s += __shfl_xor(s, off);
    if (lane == 0) {
        psum[tg] = s;
        idx_out[t] = (float)bi;
        atomicAdd(&counts[bi], 1);
    }
    __syncthreads();
    if (threadIdx.x == 0) partials[blockIdx.x] = psum[0] + psum[1] + psum[2] + psum[3];
}

// ---------------------------------------------------------------- K4: backbone + small heads (+ h in bf16)
__global__ __launch_bounds__(256) void k_backbone(
    const float* __restrict__ z_q,
    const float* __restrict__ bb1w, const float* __restrict__ bb1b,
    const float* __restrict__ bb2w, const float* __restrict__ bb2b,
    const float* __restrict__ chw, const float* __restrict__ chb,
    const float* __restrict__ lcw, const float* __restrict__ lcb,
    float* __restrict__ h_out, unsigned short* __restrict__ hbf_out,
    float* __restrict__ cont_rec, float* __restrict__ lc_out) {
    const int tid = threadIdx.x;
    const int tok0 = blockIdx.x * 16;
    __shared__ float zq[16][68];
    __shared__ float h1[16][HIDn + 4];
    __shared__ float h2[16][HIDn + 4];
    {
        int t = tid >> 4, q = tid & 15;
        ((float4*)&zq[t][0])[q] = ((const float4*)(z_q + (size_t)(tok0 + t) * EMBn))[q];
    }
    __syncthreads();
    {
        int o = tid >> 1, half = tid & 1;
        float acc[8];
        float bv = bb1b[o];
#pragma unroll
        for (int t = 0; t < 8; ++t) acc[t] = bv;
        const float4* wr = (const float4*)(bb1w + (size_t)o * EMBn);
#pragma unroll
        for (int kk = 0; kk < 16; ++kk) {
            float4 w = wr[kk];
#pragma unroll
            for (int t = 0; t < 8; ++t) acc[t] += dot4(((const float4*)&zq[half * 8 + t][0])[kk], w);
        }
#pragma unroll
        for (int t = 0; t < 8; ++t) h1[half * 8 + t][o] = fmaxf(acc[t], 0.f);
    }
    __syncthreads();
    {
        int o = tid >> 1, half = tid & 1;
        float acc[8];
        float bv = bb2b[o];
#pragma unroll
        for (int t = 0; t < 8; ++t) acc[t] = bv;
        const float4* wr = (const float4*)(bb2w + (size_t)o * HIDn);
        for (int kk = 0; kk < 32; ++kk) {
            float4 w = wr[kk];
#pragma unroll
            for (int t = 0; t < 8; ++t) acc[t] += dot4(((const float4*)&h1[half * 8 + t][0])[kk], w);
        }
#pragma unroll
        for (int t = 0; t < 8; ++t) {
            float v = fmaxf(acc[t], 0.f);
            h2[half * 8 + t][o] = v;
            h_out[(size_t)(tok0 + half * 8 + t) * HIDn + o] = v;
            hbf_out[(size_t)(tok0 + half * 8 + t) * HIDn + o] = f2bf(v);
        }
    }
    __syncthreads();
    {
        int t = tid >> 4, o = tid & 15;
        float a = chb[o];
        const float4* wr = (const float4*)(chw + (size_t)o * HIDn);
#pragma unroll
        for (int kk = 0; kk < 32; ++kk) a += dot4(((const float4*)&h2[t][0])[kk], wr[kk]);
        cont_rec[(size_t)(tok0 + t) * CONTn + o] = a;
    }
    for (int idx = tid; idx < 16 * 32; idx += 256) {
        int t = idx >> 5, o = idx & 31;
        float a = lcb[o];
        const float4* wr = (const float4*)(lcw + (size_t)o * HIDn);
#pragma unroll
        for (int kk = 0; kk < 32; ++kk) a += dot4(((const float4*)&h2[t][0])[kk], wr[kk]);
        lc_out[(size_t)(tok0 + t) * VLCn + o] = a;
    }
}

// ---------------------------------------------------------------- K5: sp_logits via bf16 MFMA, direct-from-L2 frags
__global__ __launch_bounds__(256, 3) void k_sp_mfma(
    const unsigned short* __restrict__ hbf, const unsigned short* __restrict__ wbf,
    const float* __restrict__ bias, float* __restrict__ out) {
    const int tid = threadIdx.x;
    const int lane = tid & 63;
    const int wid = tid >> 6;
    const int tok_w = blockIdx.y * 128 + (wid & 1) * 64;
    const int v_w = blockIdx.x * 128 + (wid >> 1) * 64;

    const int lrow = lane & 15;
    const int lk = (lane >> 4) * 8;

    const unsigned short* ha = hbf + (size_t)(tok_w + lrow) * HIDn + lk;
    const unsigned short* wa = wbf + (size_t)(v_w + lrow) * HIDn + lk;

    f32x4 acc[4][4];
#pragma unroll
    for (int m = 0; m < 4; ++m)
#pragma unroll
        for (int n = 0; n < 4; ++n) acc[m][n] = (f32x4){0.f, 0.f, 0.f, 0.f};

#pragma unroll
    for (int ks = 0; ks < 4; ++ks) {
        const int kk = ks * 32;
        short8v a[4], b[4];
#pragma unroll
        for (int m = 0; m < 4; ++m)
            a[m] = *(const short8v*)(ha + (size_t)m * 16 * HIDn + kk);
#pragma unroll
        for (int n = 0; n < 4; ++n)
            b[n] = *(const short8v*)(wa + (size_t)n * 16 * HIDn + kk);
#pragma unroll
        for (int m = 0; m < 4; ++m)
#pragma unroll
            for (int n = 0; n < 4; ++n)
                acc[m][n] = __builtin_amdgcn_mfma_f32_16x16x32_bf16(a[m], b[n], acc[m][n], 0, 0, 0);
    }

    const int r0 = (lane >> 4) * 4;
#pragma unroll
    for (int n = 0; n < 4; ++n) {
        const int col = v_w + n * 16 + lrow;
        if (col < VSPn) {
            const float bv = bias[col];
#pragma unroll
            for (int m = 0; m < 4; ++m) {
                const int row = tok_w + m * 16 + r0;
#pragma unroll
                for (int r = 0; r < 4; ++r)
                    out[(size_t)(row + r) * VSPn + col] = acc[m][n][r] + bv;
            }
        }
    }
}

// ---------------------------------------------------------------- K6: canopy head on h[:, -1, :]
__global__ __launch_bounds__(128) void k_canopy(const float* __restrict__ h,
                                                const float* __restrict__ w1,
                                                const float* __restrict__ b1,
                                                const float* __restrict__ w2,
                                                const float* __restrict__ b2,
                                                float* __restrict__ can) {
    int b = blockIdx.x, o = threadIdx.x;
    __shared__ float r[128];
    const float4* hr = (const float4*)(h + (size_t)(b * Tn + Tn - 1) * HIDn);
    const float4* wr = (const float4*)(w1 + (size_t)o * HIDn);
    float a = b1[o];
#pragma unroll
    for (int kk = 0; kk < 32; ++kk) a += dot4(hr[kk], wr[kk]);
    r[o] = fmaxf(a, 0.f) * w2[o];
    __syncthreads();
    for (int s = 64; s > 0; s >>= 1) {
        if (o < s) r[o] += r[o + s];
        __syncthreads();
    }
    if (o == 0) can[b] = r[0] + b2[0];
}

// ---------------------------------------------------------------- K7: loss + perplexity
__global__ __launch_bounds__(256) void k_finalize(const float* __restrict__ partials,
                                                  const int* __restrict__ counts,
                                                  float* __restrict__ out_loss,
                                                  float* __restrict__ out_ppl) {
    const int tid = threadIdx.x;
    __shared__ float red[256];
    float ps = 0.f;
#pragma unroll
    for (int j = 0; j < (BTn / 4) / 256; ++j) ps += partials[tid * ((BTn / 4) / 256) + j];
    red[tid] = ps;
    __syncthreads();
    for (int s = 128; s > 0; s >>= 1) {
        if (tid < s) red[tid] += red[tid + s];
        __syncthreads();
    }
    float total = red[0];
    __syncthreads();
    float e = 0.f;
    for (int i = tid; i < Kn; i += 256) {
        float p = (float)counts[i] * (1.0f / BTn);
        e += p * logf(p + 1e-12f);
    }
    red[tid] = e;
    __syncthreads();
    for (int s = 128; s > 0; s >>= 1) {
        if (tid < s) red[tid] += red[tid + s];
        __syncthreads();
    }
    if (tid == 0) {
        out_loss[0] = 1.25f * total / (float)((size_t)BTn * EMBn);
        out_ppl[0] = expf(-red[0]);
    }
}

// ----------------------------------------------------------------
extern "C" void kernel_launch(void* const* d_in, const int* in_sizes, int n_in,
                              void* d_out, int out_size, void* d_ws, size_t ws_size,
                              hipStream_t stream) {
    const float* cont = (const float*)d_in[0];
    const float* naip = (const float*)d_in[1];
    const int* cat = (const int*)d_in[2];
    const float* emb_sp = (const float*)d_in[3];
    const float* emb_lc = (const float*)d_in[4];
    const float* conv_w = (const float*)d_in[5];
    const float* conv_b = (const float*)d_in[6];
    const float* npw = (const float*)d_in[7];
    const float* npb = (const float*)d_in[8];
    const float* cpw = (const float*)d_in[9];
    const float* cpb = (const float*)d_in[10];
    const float* caw = (const float*)d_in[11];
    const float* cab = (const float*)d_in[12];
    const float* f1w = (const float*)d_in[13];
    const float* f1b = (const float*)d_in[14];
    const float* f2w = (const float*)d_in[15];
    const float* f2b = (const float*)d_in[16];
    const float* cb = (const float*)d_in[17];
    const float* bb1w = (const float*)d_in[18];
    const float* bb1b = (const float*)d_in[19];
    const float* bb2w = (const float*)d_in[20];
    const float* bb2b = (const float*)d_in[21];
    const float* chw = (const float*)d_in[22];
    const float* chb = (const float*)d_in[23];
    const float* spw = (const float*)d_in[24];
    const float* spb = (const float*)d_in[25];
    const float* lcw = (const float*)d_in[26];
    const float* lcb = (const float*)d_in[27];
    const float* c1w = (const float*)d_in[28];
    const float* c1b = (const float*)d_in[29];
    const float* c2w = (const float*)d_in[30];
    const float* c2b = (const float*)d_in[31];

    float* out = (float*)d_out;
    float* ws = (float*)d_ws;
    float* naip2 = ws + WS_NAIP2;
    float* z_e = ws + WS_ZE;
    float* z_q = ws + WS_ZQ;
    float* h = ws + WS_H;
    float* e_sq = ws + WS_ESQ;
    float* parts = ws + WS_PART;
    int* counts = (int*)(ws + WS_CNTK);
    int* cntT = (int*)(ws + WS_CNTT);
    float* qtok = ws + WS_Q;
    int* cand = (int*)(ws + WS_CAND);
    unsigned short* zbf = (unsigned short*)(ws + WS_ZBF);
    unsigned short* cbbf = (unsigned short*)(ws + WS_CBBF);
    unsigned short* hbf = (unsigned short*)(ws + WS_HBF);
    unsigned short* wbf = (unsigned short*)(ws + WS_WBF);
    float* rcg = ws + WS_RCG;

    k_esq_zero<<<dim3(Kn / 256), dim3(256), 0, stream>>>(cb, e_sq, counts, cbbf);
    k_rcmax<<<dim3(1), dim3(256), 0, stream>>>(e_sq, rcg);
    k_wcast<<<dim3(VSP_PAD * HIDn / 4 / 256), dim3(256), 0, stream>>>(spw, wbf);
    k_naip<<<dim3(Bn), dim3(128), 0, stream>>>(naip, conv_w, conv_b, npw, npb, naip2);
    k_ze<<<dim3(BTn / 32), dim3(256), 0, stream>>>(cont, cat, emb_sp, emb_lc, cpw, cpb, caw, cab,
                                                   f1w, f1b, f2w, f2b, naip2, z_e);
    k_zprep<<<dim3(BTn / 4), dim3(256), 0, stream>>>(z_e, zbf, qtok);
    k_vq_sweep<<<dim3(BTn / TOKB), dim3(512), 0, stream>>>(zbf, cbbf, e_sq, qtok, rcg, cntT, cand);
    k_vq_rescore<<<dim3(BTn / 4), dim3(256), 0, stream>>>(cntT, cand, z_e, cb, e_sq, z_q,
                                                          out + O_IDX, counts, parts);
    k_backbone<<<dim3(BTn / 16), dim3(256), 0, stream>>>(z_q, bb1w, bb1b, bb2w, bb2b, chw, chb,
                                                         lcw, lcb, h, hbf, out + O_CONT, out + O_LC);
    k_sp_mfma<<<dim3(VSP_PAD / 128, BTn / 128), dim3(256), 0, stream>>>(hbf, wbf, spb, out + O_SP);
    k_canopy<<<dim3(Bn), dim3(128), 0, stream>>>(h, c1w, c1b, c2w, c2b, out + O_CAN);
    k_finalize<<<dim3(1), dim3(256), 0, stream>>>(parts, counts, out + O_LOSS, out + O_PPL);
}